// Round 7
// baseline (1214.544 us; speedup 1.0000x reference)
//
#include <hip/hip_runtime.h>
#include <math.h>

#define NB 128
#define SEQ 17
#define DM 192
#define DI 384
#define DEPTH 12
#define ROW (SEQ*DM)       // 3264
#define NROWS 4352         // 2*NB*SEQ
#define N192 (NROWS*DM)    // 835584
#define C1IP (DEPTH*2*DI*DM)   // 1769472 (one stream's in_proj elements)
#define C2OP (DEPTH*DM*DI)     // 884736  (one stream's out_proj elements)
#define KEMB 1792
#define CEMB_STRIDE 786432     // 4096*192, one K-partial of the embed gemm

typedef __attribute__((ext_vector_type(8))) short bf16x8;
typedef __attribute__((ext_vector_type(4))) float f32x4;

struct MambaW {
  const float* norm_w;
  const float* in_proj;
  const float* conv_w;
  const float* conv_b;
  const float* x_proj;
  const float* dt_w;
  const float* dt_b;
  const float* A_log;
  const float* D;
  const float* out_proj;
};

__device__ __forceinline__ float dot4(float4 a, float4 b) {
  return a.x*b.x + a.y*b.y + a.z*b.z + a.w*b.w;
}
__device__ __forceinline__ unsigned short f2bf(float f) {
  unsigned int u = __float_as_uint(f);
  u += 0x7FFFu + ((u >> 16) & 1u);
  return (unsigned short)(u >> 16);
}
__device__ __forceinline__ float bf2f(unsigned short h) {
  return __uint_as_float(((unsigned int)h) << 16);
}
__device__ __forceinline__ void split2(float v, unsigned short& h, unsigned short& l) {
  h = f2bf(v);
  l = f2bf(v - bf2f(h));
}

// ---------------------------------------------------------------------------
// Weight decompose fp32 -> bf16 hi/lo. (verified R4)
// ---------------------------------------------------------------------------
__global__ __launch_bounds__(256) void decomp_kernel(
    const float* __restrict__ s0, const float* __restrict__ s1,
    unsigned short* __restrict__ hi, unsigned short* __restrict__ lo, int nquads)
{
  const float* s = blockIdx.y ? s1 : s0;
  size_t base = (size_t)blockIdx.y * nquads;
  for (size_t i = (size_t)blockIdx.x*256 + threadIdx.x; i < (size_t)nquads;
       i += (size_t)gridDim.x*256) {
    float4 v = ((const float4*)s)[i];
    ushort4 h, l;
    split2(v.x, h.x, l.x); split2(v.y, h.y, l.y);
    split2(v.z, h.z, l.z); split2(v.w, h.w, l.w);
    ((ushort4*)hi)[base + i] = h;
    ((ushort4*)lo)[base + i] = l;
  }
}

// ---------------------------------------------------------------------------
// f-stream transpose (verified R10).
// ---------------------------------------------------------------------------
__global__ __launch_bounds__(256) void prep_kernel(
    const float* __restrict__ x, float* __restrict__ Af)
{
  const int t = threadIdx.x;
  const int b = blockIdx.x >> 3, c = blockIdx.x & 7;
  const float* xp = x + (size_t)(b*8 + c)*3584;
  __shared__ float ts[16][225];
  for (int idx = t; idx < 3584; idx += 256)
    ts[idx & 15][idx >> 4] = xp[idx];
  __syncthreads();
  for (int i4 = t; i4 < 896; i4 += 256) {
    const int p = i4 / 56, r4 = (i4 - p*56)*4;
    float4 v;
    v.x = ts[p][r4]; v.y = ts[p][r4+1]; v.z = ts[p][r4+2]; v.w = ts[p][r4+3];
    *(float4*)&Af[(size_t)(b*16 + p)*KEMB + c*224 + r4] = v;
  }
}

// ---------------------------------------------------------------------------
// fp32 embed GEMM v3 (verified R11).
// ---------------------------------------------------------------------------
__global__ __launch_bounds__(256) void gemm_embed(
    const float* __restrict__ x, const float* __restrict__ Af,
    const float* __restrict__ Wt, const float* __restrict__ Wf,
    float* __restrict__ C)
{
  const int t = threadIdx.x;
  const int mt = blockIdx.x, nt = blockIdx.y, kz = blockIdx.z;
  __shared__ float As[32][68];
  __shared__ float Bs[32][68];

  const float* Wsel = (nt < 32 ? Wt : Wf) + (size_t)(mt*64)*KEMB;

  const int srow = t >> 2;
  const int a8   = t & 3;
  const int sw   = (a8 & 1) << 4;
  const int colA = srow ^ sw;

  const int tn = t & 15;
  const int tm = t >> 4;
  float acc[4][4];
#pragma unroll
  for (int i = 0; i < 4; ++i)
#pragma unroll
    for (int j = 0; j < 4; ++j) acc[i][j] = 0.f;

  const int kbase = kz*448;
  const float* xrowbase = nullptr;
  const float* afrow    = nullptr;
  if (nt < 32) {
    const int r = nt*64 + srow;
    const int b = r >> 4, p = r & 15;
    xrowbase = x + (size_t)(b*8)*3584 + p*224 + a8*8;
  } else {
    const int r = (nt - 32)*64 + srow;
    afrow = Af + (size_t)r*KEMB + kbase + a8*8;
  }
  const float* brow = Wsel + (size_t)srow*KEMB + kbase + a8*8;

  int cblk = kz*2, rr = 0;
  float4 pa0, pa1, pb0, pb1;
  {
    const float* ar = (nt < 32) ? (xrowbase + (size_t)cblk*3584 + rr) : afrow;
    pa0 = *(const float4*)(ar + 0);
    pa1 = *(const float4*)(ar + 4);
    pb0 = *(const float4*)(brow + 0);
    pb1 = *(const float4*)(brow + 4);
  }

  for (int kt = 0; kt < 448; kt += 32) {
    As[a8*8+0][colA]=pa0.x; As[a8*8+1][colA]=pa0.y;
    As[a8*8+2][colA]=pa0.z; As[a8*8+3][colA]=pa0.w;
    As[a8*8+4][colA]=pa1.x; As[a8*8+5][colA]=pa1.y;
    As[a8*8+6][colA]=pa1.z; As[a8*8+7][colA]=pa1.w;
    Bs[a8*8+0][colA]=pb0.x; Bs[a8*8+1][colA]=pb0.y;
    Bs[a8*8+2][colA]=pb0.z; Bs[a8*8+3][colA]=pb0.w;
    Bs[a8*8+4][colA]=pb1.x; Bs[a8*8+5][colA]=pb1.y;
    Bs[a8*8+6][colA]=pb1.z; Bs[a8*8+7][colA]=pb1.w;
    __syncthreads();
    if (kt + 32 < 448) {
      rr += 32; if (rr == 224) { rr = 0; ++cblk; }
      const float* ar = (nt < 32) ? (xrowbase + (size_t)cblk*3584 + rr)
                                  : (afrow + kt + 32);
      pa0 = *(const float4*)(ar + 0);
      pa1 = *(const float4*)(ar + 4);
      const float* br = brow + kt + 32;
      pb0 = *(const float4*)(br + 0);
      pb1 = *(const float4*)(br + 4);
    }
#pragma unroll
    for (int kk = 0; kk < 32; ++kk) {
      const int xr = ((kk >> 3) & 1) << 4;
      float a[4], b[4];
      *(float4*)&a[0] = *(const float4*)&As[kk][(tn*4) ^ xr];
      *(float4*)&b[0] = *(const float4*)&Bs[kk][(tm*4) ^ xr];
#pragma unroll
      for (int i = 0; i < 4; ++i)
#pragma unroll
        for (int j = 0; j < 4; ++j) acc[i][j] = fmaf(a[i], b[j], acc[i][j]);
    }
    __syncthreads();
  }

  float* Cb = C + (size_t)kz*CEMB_STRIDE
            + (size_t)(nt*64 + tn*4)*DM + mt*64 + tm*4;
#pragma unroll
  for (int i = 0; i < 4; ++i)
    *(float4*)(Cb + (size_t)i*DM) = *(float4*)&acc[i][0];
}

// ---------------------------------------------------------------------------
// Split-bf16 MFMA GEMM. R14: register prefetch (issue-early / write-late) —
// the K-loop is only 6 kt-steps and previously serialized
// barrier->global-load->barrier->compute; now the next tile's loads are in
// flight during ds_read+MFMA (same technique that fixed gemm_embed in R11).
// Math, LDS layout, and operand mapping byte-identical to verified R4.
// ---------------------------------------------------------------------------
template<int MT>
__global__ __launch_bounds__(256) void gemm_mfma(
    const unsigned short* __restrict__ Ahi, const unsigned short* __restrict__ Alo, int lda,
    const unsigned short* __restrict__ BtHi, const unsigned short* __restrict__ BtLo,
    const unsigned short* __restrict__ BfHi, const unsigned short* __restrict__ BfLo,
    int ldb, int kchunk, float* __restrict__ C, int ldc, long ckstride)
{
  const int t = threadIdx.x;
  const int mt = blockIdx.x, nt = blockIdx.y, kz = blockIdx.z;
  __shared__ alignas(16) unsigned short sAh[64*40], sAl[64*40];
  __shared__ alignas(16) unsigned short sBh[MT*40], sBl[MT*40];

  const bool isT = (nt < 34);
  const int srow = t >> 2, sseg = (t & 3) * 8;

  const unsigned short* aHp = Ahi + (size_t)(nt*64 + srow)*lda + kz*kchunk + sseg;
  const unsigned short* aLp = Alo + (size_t)(nt*64 + srow)*lda + kz*kchunk + sseg;
  const unsigned short* bHb = (isT ? BtHi : BfHi) + (size_t)(mt*MT)*ldb + kz*kchunk + sseg;
  const unsigned short* bLb = (isT ? BtLo : BfLo) + (size_t)(mt*MT)*ldb + kz*kchunk + sseg;

  const int wave = t >> 6, lane = t & 63;
  const int arow = wave*16 + (lane & 15);
  const int kb   = (lane >> 4) * 8;

  f32x4 acc[MT/16];
#pragma unroll
  for (int mb = 0; mb < MT/16; ++mb) acc[mb] = (f32x4){0.f, 0.f, 0.f, 0.f};

  uint4 pah, pal, pbh[MT/64], pbl[MT/64];
  pah = *(const uint4*)(aHp);
  pal = *(const uint4*)(aLp);
#pragma unroll
  for (int rep = 0; rep < MT/64; ++rep) {
    pbh[rep] = *(const uint4*)(bHb + (size_t)(rep*64 + srow)*ldb);
    pbl[rep] = *(const uint4*)(bLb + (size_t)(rep*64 + srow)*ldb);
  }

  for (int kt = 0; kt < kchunk; kt += 32) {
    // write-late: prefetched regs -> LDS
    *(uint4*)(sAh + srow*40 + sseg) = pah;
    *(uint4*)(sAl + srow*40 + sseg) = pal;
#pragma unroll
    for (int rep = 0; rep < MT/64; ++rep) {
      *(uint4*)(sBh + (rep*64 + srow)*40 + sseg) = pbh[rep];
      *(uint4*)(sBl + (rep*64 + srow)*40 + sseg) = pbl[rep];
    }
    __syncthreads();
    // issue-early: next kt's global loads in flight during compute
    if (kt + 32 < kchunk) {
      pah = *(const uint4*)(aHp + kt + 32);
      pal = *(const uint4*)(aLp + kt + 32);
#pragma unroll
      for (int rep = 0; rep < MT/64; ++rep) {
        pbh[rep] = *(const uint4*)(bHb + (size_t)(rep*64 + srow)*ldb + kt + 32);
        pbl[rep] = *(const uint4*)(bLb + (size_t)(rep*64 + srow)*ldb + kt + 32);
      }
    }
    bf16x8 ah = *(const bf16x8*)(sAh + arow*40 + kb);
    bf16x8 al = *(const bf16x8*)(sAl + arow*40 + kb);
#pragma unroll
    for (int mb = 0; mb < MT/16; ++mb) {
      bf16x8 bh = *(const bf16x8*)(sBh + (mb*16 + (lane & 15))*40 + kb);
      bf16x8 bl = *(const bf16x8*)(sBl + (mb*16 + (lane & 15))*40 + kb);
      acc[mb] = __builtin_amdgcn_mfma_f32_16x16x32_bf16(al, bh, acc[mb], 0, 0, 0);
      acc[mb] = __builtin_amdgcn_mfma_f32_16x16x32_bf16(ah, bl, acc[mb], 0, 0, 0);
      acc[mb] = __builtin_amdgcn_mfma_f32_16x16x32_bf16(ah, bh, acc[mb], 0, 0, 0);
    }
    __syncthreads();
  }

  float* Cb = C + (long)kz*ckstride
            + (size_t)(nt*64 + wave*16 + (lane >> 4)*4)*ldc + mt*MT + (lane & 15);
#pragma unroll
  for (int mb = 0; mb < MT/16; ++mb)
#pragma unroll
    for (int r = 0; r < 4; ++r)
      Cb[(size_t)r*ldc + mb*16] = acc[mb][r];
}

// ---------------------------------------------------------------------------
// Embed epilogue (verified R11).
// ---------------------------------------------------------------------------
__global__ __launch_bounds__(192) void embed_fin_kernel(
    const float* __restrict__ Cg,
    const float* __restrict__ bT, const float* __restrict__ posT,
    const float* __restrict__ tokT, const float* __restrict__ nwT,
    const float* __restrict__ bF, const float* __restrict__ posF,
    const float* __restrict__ tokF, const float* __restrict__ nwF,
    float* __restrict__ res,
    unsigned short* __restrict__ hHi, unsigned short* __restrict__ hLo)
{
  const int d = threadIdx.x;
  const int sb = blockIdx.x;
  const int is_f = sb >> 7, b = sb & 127;
  const float* bias = is_f ? bF : bT;
  const float* pos  = is_f ? posF : posT;
  const float* tok  = is_f ? tokF : tokT;
  const float* nw   = is_f ? nwF : nwT;
  __shared__ float sq[SEQ*192];
  __shared__ float pt[SEQ*8];
  __shared__ float sc[SEQ];

  float v[SEQ];
  const float* Crow = Cg + ((size_t)is_f*2048 + (size_t)b*16)*DM + d;
  const float add = bias[d];
#pragma unroll
  for (int l = 0; l < 16; ++l) {
    v[l] = (Crow[l*DM] + Crow[(size_t)CEMB_STRIDE + l*DM])
         + (Crow[(size_t)2*CEMB_STRIDE + l*DM] + Crow[(size_t)3*CEMB_STRIDE + l*DM])
         + add + pos[l*DM + d];
    sq[l*192 + d] = v[l]*v[l];
  }
  v[16] = tok[d] + pos[16*DM + d];
  sq[16*192 + d] = v[16]*v[16];
  __syncthreads();
  if (d < 136) {
    int l = d >> 3, j = d & 7;
    float s = 0.f;
#pragma unroll
    for (int q = 0; q < 24; ++q) s += sq[l*192 + j + 8*q];
    pt[d] = s;
  }
  __syncthreads();
  if (d < SEQ) {
    float s = 0.f;
#pragma unroll
    for (int j = 0; j < 8; ++j) s += pt[d*8 + j];
    sc[d] = rsqrtf(s*(1.0f/192.0f) + 1e-5f);
  }
  __syncthreads();
  float nwd = nw[d];
#pragma unroll
  for (int l = 0; l < SEQ; ++l) {
    size_t idx = ((size_t)sb*SEQ + l)*DM + d;
    res[idx] = v[l];
    unsigned short h, lo_;
    split2(v[l]*sc[l]*nwd, h, lo_);
    hHi[idx] = h; hLo[idx] = lo_;
  }
}

// ---------------------------------------------------------------------------
// mid_kernel (R13 remap verified: broadcast-friendly x_proj mapping).
// ---------------------------------------------------------------------------
__global__ __launch_bounds__(384) void mid_kernel(
    const float* __restrict__ xzg,
    unsigned short* __restrict__ yHi, unsigned short* __restrict__ yLo,
    MambaW wt, MambaW wf, int layer)
{
  const int t = threadIdx.x;
  const int sb = blockIdx.x;
  const MambaW W = (sb >= NB) ? wf : wt;
  __shared__ alignas(16) float lds_xx[SEQ*388];
  __shared__ alignas(16) float lds_dbl[748];
  const size_t nb = (size_t)sb*SEQ;

  float xr[SEQ];
  {
    const float4 cw = ((const float4*)(W.conv_w + (size_t)layer*DI*4))[t];
    const float cb = W.conv_b[layer*DI + t];
    float p0 = 0.f, p1 = 0.f, p2 = 0.f;
#pragma unroll
    for (int l = 0; l < SEQ; ++l) {
      float xz = xzg[(nb + l)*768 + t];
      float v = cb + xz*cw.w + p0*cw.z + p1*cw.y + p2*cw.x;
      p2 = p1; p1 = p0; p0 = xz;
      v = v / (1.f + __expf(-v));
      xr[l] = v;
      lds_xx[l*388 + t] = v;
    }
  }
  __syncthreads();

  {
    const float* XP = W.x_proj + (size_t)layer*44*DI;
#pragma unroll
    for (int rep = 0; rep < 2; ++rep) {
      int o = t + rep*384;
      if (o < 748) {
        int j = o / 17, l = o - j*17;          // R13 remap
        const float4* wr = (const float4*)(XP + j*DI);
        const float4* xv4 = (const float4*)lds_xx + l*97;
        float a = 0.f;
        for (int k4 = 0; k4 < 96; ++k4) a += dot4(xv4[k4], wr[k4]);
        lds_dbl[l*44 + j] = a;
      }
    }
  }
  __syncthreads();

  {
    const int c = t;
    const float* dwr = W.dt_w + (size_t)layer*DI*12 + c*12;
    float w0[12];
#pragma unroll
    for (int r = 0; r < 12; ++r) w0[r] = dwr[r];
    const float dtb = W.dt_b[layer*DI + c];
    const float4* alr = (const float4*)(W.A_log + (size_t)layer*DI*16) + c*4;
    float Av[16];
#pragma unroll
    for (int q = 0; q < 4; ++q) {
      float4 a4 = alr[q];
      Av[q*4+0] = -__expf(a4.x); Av[q*4+1] = -__expf(a4.y);
      Av[q*4+2] = -__expf(a4.z); Av[q*4+3] = -__expf(a4.w);
    }
    const float Dp = W.D[layer*DI + c];
    float hst[16];
#pragma unroll
    for (int n = 0; n < 16; ++n) hst[n] = 0.f;
    for (int l = 0; l < SEQ; ++l) {
      float a = dtb;
#pragma unroll
      for (int r = 0; r < 12; ++r) a += lds_dbl[l*44 + r]*w0[r];
      float dt = (a > 20.f) ? a : log1pf(__expf(a));
      float xv = xr[l];
      const float4* dbv = (const float4*)(lds_dbl + l*44 + 12);
      float4 Bq[4], Cq[4];
      Bq[0]=dbv[0]; Bq[1]=dbv[1]; Bq[2]=dbv[2]; Bq[3]=dbv[3];
      Cq[0]=dbv[4]; Cq[1]=dbv[5]; Cq[2]=dbv[6]; Cq[3]=dbv[7];
      const float* Bs = (const float*)Bq;
      const float* Cs = (const float*)Cq;
      float y = 0.f;
      float dbx = dt * xv;
#pragma unroll
      for (int n = 0; n < 16; ++n) {
        float dA = __expf(dt * Av[n]);
        float hn = dA*hst[n] + dbx*Bs[n];
        hst[n] = hn;
        y += hn*Cs[n];
      }
      y += Dp * xv;
      float zv = xzg[(nb + l)*768 + DI + c];
      y *= zv / (1.f + __expf(-zv));
      unsigned short h, lo_;
      split2(y, h, lo_);
      size_t idx = (nb + l)*DI + c;
      yHi[idx] = h; yLo[idx] = lo_;
    }
  }
}

// ---------------------------------------------------------------------------
// Sum 2 K-split partials + residual + RMSNorm (verified R4).
// ---------------------------------------------------------------------------
__global__ __launch_bounds__(192) void fuse_kernel(
    const float* __restrict__ part, float* __restrict__ res,
    unsigned short* __restrict__ hHi, unsigned short* __restrict__ hLo,
    float* __restrict__ xfin,
    const float* __restrict__ nwT, const float* __restrict__ nwF,
    int layer, int last)
{
  const int d = threadIdx.x;
  const int sb = blockIdx.x;
  const size_t nb = (size_t)sb*SEQ;
  __shared__ float sq[SEQ*192];
  __shared__ float pt[SEQ*8];
  __shared__ float sc[SEQ];

  float v[SEQ];
#pragma unroll
  for (int l = 0; l < SEQ; ++l) {
    size_t idx = (nb + l)*DM + d;
    float s = part[idx] + part[(size_t)N192 + idx];
    if (!last) {
      s += res[idx];
      res[idx] = s;
      v[l] = s;
      sq[l*192 + d] = s*s;
    } else {
      xfin[idx] = s;
    }
  }
  if (last) return;
  __syncthreads();
  if (d < 136) {
    int l = d >> 3, j = d & 7;
    float s = 0.f;
#pragma unroll
    for (int q = 0; q < 24; ++q) s += sq[l*192 + j + 8*q];
    pt[d] = s;
  }
  __syncthreads();
  if (d < SEQ) {
    float s = 0.f;
#pragma unroll
    for (int j = 0; j < 8; ++j) s += pt[d*8 + j];
    sc[d] = rsqrtf(s*(1.0f/192.0f) + 1e-5f);
  }
  __syncthreads();
  const float* nw = ((sb < NB) ? nwT : nwF) + (size_t)(layer + 1)*DM;
  float nwd = nw[d];
#pragma unroll
  for (int l = 0; l < SEQ; ++l) {
    unsigned short h, lo_;
    split2(v[l]*sc[l]*nwd, h, lo_);
    size_t idx = (nb + l)*DM + d;
    hHi[idx] = h; hLo[idx] = lo_;
  }
}

// ---------------------------------------------------------------------------
// Attention K/V GEMM (fp32 VALU, verified R3/R4). grid (8,17).
// ---------------------------------------------------------------------------
__global__ __launch_bounds__(256, 3) void gemm_kv(
    const float* __restrict__ A, int lda, int ktot,
    const float* __restrict__ Bt, const float* __restrict__ Bf, int ldb,
    const float* __restrict__ bias1, const float* __restrict__ bias2,
    float* __restrict__ C, int ldc)
{
  const int t  = threadIdx.x;
  const int mt = blockIdx.x, nt = blockIdx.y;
  __shared__ float As[32][132];
  __shared__ float Bs[32][100];

  int pass = mt >> 2, kv = (mt >> 1) & 1, half = mt & 1;
  const float* Bp = (pass ? Bf : Bt) + (size_t)(1+kv)*DM*DM + (size_t)(half*96)*ldb;
  const float* bp = (pass ? bias2 : bias1) + (1+kv)*DM + half*96;
  const float* Ap = A + (size_t)(nt*128)*lda;

  const int tn = t & 15, tm = t >> 4;
  float acc[8][6];
#pragma unroll
  for (int i = 0; i < 8; ++i)
#pragma unroll
    for (int j = 0; j < 6; ++j) acc[i][j] = 0.f;

  const int srow = t >> 1;
  const int skl  = (t & 1) * 16;

  for (int kt = 0; kt < ktot; kt += 32) {
    __syncthreads();
    {
      const float* ar = Ap + (size_t)srow*lda + kt + skl;
      float4 v0 = *(const float4*)(ar + 0);
      float4 v1 = *(const float4*)(ar + 4);
      float4 v2 = *(const float4*)(ar + 8);
      float4 v3 = *(const float4*)(ar + 12);
      As[skl+ 0][srow]=v0.x; As[skl+ 1][srow]=v0.y; As[skl+ 2][srow]=v0.z; As[skl+ 3][srow]=v0.w;
      As[skl+ 4][srow]=v1.x; As[skl+ 5][srow]=v1.y; As[skl+ 6][srow]=v1.z; As[skl+ 7][srow]=v1.w;
      As[skl+ 8][srow]=v2.x; As[skl+ 9][srow]=v2.y; As[skl+10][srow]=v2.z; As[skl+11][srow]=v2.w;
      As[skl+12][srow]=v3.x; As[skl+13][srow]=v3.y; As[skl+14][srow]=v3.z; As[skl+15][srow]=v3.w;
    }
    if (srow < 96) {
      const float* br = Bp + (size_t)srow*ldb + kt + skl;
      float4 v0 = *(const float4*)(br + 0);
      float4 v1 = *(const float4*)(br + 4);
      float4 v2 = *(const float4*)(br + 8);
      float4 v3 = *(const float4*)(br + 12);
      Bs[skl+ 0][srow]=v0.x; Bs[skl+ 1][srow]=v0.y; Bs[skl+ 2][srow]=v0.z; Bs[skl+ 3][srow]=v0.w;
      Bs[skl+ 4][srow]=v1.x; Bs[skl+ 5][srow]=v1.y; Bs[skl+ 6][srow]=v1.z; Bs[skl+ 7][srow]=v1.w;
      Bs[skl+ 8][srow]=v2.x; Bs[skl+ 9][srow]=v2.y; Bs[skl+10][srow]=v2.z; Bs[skl+11][srow]=v2.w;
      Bs[skl+12][srow]=v3.x; Bs[skl+13][srow]=v3.y; Bs[skl+14][srow]=v3.z; Bs[skl+15][srow]=v3.w;
    }
    __syncthreads();
#pragma unroll
    for (int kk = 0; kk < 32; ++kk) {
      float a[8], b[6];
      *(float4*)&a[0] = *(const float4*)&As[kk][tn*4];
      *(float4*)&a[4] = *(const float4*)&As[kk][64 + tn*4];
      *(float2*)&b[0] = *(const float2*)&Bs[kk][tm*6];
      *(float2*)&b[2] = *(const float2*)&Bs[kk][tm*6+2];
      *(float2*)&b[4] = *(const float2*)&Bs[kk][tm*6+4];
#pragma unroll
      for (int i = 0; i < 8; ++i)
#pragma unroll
        for (int j = 0; j < 6; ++j) acc[i][j] = fmaf(a[i], b[j], acc[i][j]);
    }
  }

  float* Cb = C + (size_t)(nt*128)*ldc + mt*96;
#pragma unroll
  for (int ni = 0; ni < 8; ++ni) {
    int n = (ni < 4) ? tn*4 + ni : 64 + tn*4 + (ni - 4);
    float* cr = Cb + (size_t)n*ldc;
#pragma unroll
    for (int j = 0; j < 6; ++j) cr[tm*6 + j] = acc[ni][j] + bp[tm*6 + j];
  }
}

// ---------------------------------------------------------------------------
// R14 coop GEMV: register prefetch (R13) + conflict-free staging. R13's
// per-lane float4 writes had banks (r+4t)%32 -> lanes t,t+8,.. collide
// (6-way, 4.6M conflicts). Scalar indexing flat = t + 256*i gives lane-
// consecutive addresses -> consecutive banks -> 0 conflicts; global side
// stays coalesced (b32 wave loads); register count unchanged (48 floats).
// Compute-side reads (stride-193 rows) were already conflict-free.
// ---------------------------------------------------------------------------
__device__ __forceinline__ void coop_gemv192(
    const float* __restrict__ W, const float* __restrict__ bias,
    const float* __restrict__ xv, float* __restrict__ y,
    const float* __restrict__ addv, int nout, int relu,
    float* __restrict__ wbuf, float* __restrict__ pt, int t)
{
  float pv[48];
#pragma unroll
  for (int i = 0; i < 48; ++i) pv[i] = W[t + i*256];
  for (int d0 = 0; d0 < nout; d0 += 64) {
    {
      // flat = t + 256*i ; r = flat/192, c = flat%192, addr = 193r + c.
      // incremental: i->i+1 adds r+=1,c+=64 (addr+=257); wrap adds +1 more r
      // minus 192 c (addr+=258 total).
      int r0 = t / 192;
      int c0 = t - r0*192;
      int addr = r0*193 + c0;
      int c = c0;
#pragma unroll
      for (int i = 0; i < 48; ++i) {
        wbuf[addr] = pv[i];
        c += 64;
        const int wrap = (c >= 192);
        c -= wrap ? 192 : 0;
        addr += wrap ? 258 : 257;
      }
    }
    __syncthreads();
    if (d0 + 64 < nout) {
      const float* nsrc = W + (size_t)(d0+64)*192;
#pragma unroll
      for (int i = 0; i < 48; ++i) pv[i] = nsrc[t + i*256];
    }
    {
      const int ol = t & 63, ks = t >> 6;
      const float* wr = wbuf + ol*193 + ks*48;
      const float* xr = xv + ks*48;
      float a = 0.f;
#pragma unroll
      for (int k = 0; k < 48; ++k) a = fmaf(wr[k], xr[k], a);
      pt[ks*64 + ol] = a;
    }
    __syncthreads();
    if (t < 64) {
      float s = (pt[t] + pt[64+t]) + (pt[128+t] + pt[192+t]) + bias[d0+t];
      if (addv) s += addv[d0+t];
      if (relu) s = fmaxf(s, 0.f);
      y[d0+t] = s;
    }
    __syncthreads();
  }
}

// ---------------------------------------------------------------------------
// attn_core (R13 structure: grid 256 = (b, path), both paths share the
// attention/feat section, path 0 = cls MLP+head, path 1 = pos MLP+head).
// ---------------------------------------------------------------------------
__global__ __launch_bounds__(256) void attn_core_kernel(
    const float* __restrict__ xfin, const float* __restrict__ kvg,
    const float* __restrict__ w1, const float* __restrict__ b1,
    const float* __restrict__ w2, const float* __restrict__ b2,
    const float* __restrict__ c1w, const float* __restrict__ c1b,
    const float* __restrict__ c2w, const float* __restrict__ c2b,
    const float* __restrict__ p1w, const float* __restrict__ p1b,
    const float* __restrict__ p2w, const float* __restrict__ p2b,
    float* __restrict__ out)
{
  const int t = threadIdx.x;
  const int b = blockIdx.x >> 1;
  const int path = blockIdx.x & 1;
  __shared__ float wbuf[64*193];
  __shared__ float pt[256];
  __shared__ float pth[256];
  __shared__ alignas(16) float t16[DM];
  __shared__ alignas(16) float qv[DM];
  __shared__ alignas(16) float ov[DM];
  __shared__ alignas(16) float t1[DM];
  __shared__ alignas(16) float feat[DM];
  __shared__ alignas(16) float hbuf[512];

  if (t < DM) t16[t] = xfin[((size_t)b*SEQ + 16)*DM + t];
  __syncthreads();

  for (int pass = 0; pass < 2; ++pass) {
    const float* wa = pass ? w2 : w1;
    const float* ba = pass ? b2 : b1;
    coop_gemv192(wa, ba, pass ? t1 : t16, qv, nullptr, DM, 0, wbuf, pt, t);
    if (t < DM) {
      int h = t / 24;
      float4 q0 = *(const float4*)&qv[h*24];
      float4 q1 = *(const float4*)&qv[h*24+4];
      float4 q2 = *(const float4*)&qv[h*24+8];
      float4 q3 = *(const float4*)&qv[h*24+12];
      float4 q4 = *(const float4*)&qv[h*24+16];
      float4 q5 = *(const float4*)&qv[h*24+20];
      float scs[SEQ];
      float mx = -1e30f;
#pragma unroll
      for (int lk = 0; lk < SEQ; ++lk) {
        const float4* kr = (const float4*)(kvg + ((size_t)b*SEQ + lk)*768 + pass*384 + h*24);
        float s_ = dot4(q0,kr[0]) + dot4(q1,kr[1]) + dot4(q2,kr[2])
                 + dot4(q3,kr[3]) + dot4(q4,kr[4]) + dot4(q5,kr[5]);
        s_ *= 0.20412414523193154f;
        scs[lk] = s_;
        mx = fmaxf(mx, s_);
      }
      float den = 0.f;
#pragma unroll
      for (int lk = 0; lk < SEQ; ++lk) { float e = __expf(scs[lk]-mx); scs[lk]=e; den += e; }
      float inv = 1.f/den;
      float o = 0.f;
#pragma unroll
      for (int lk = 0; lk < SEQ; ++lk)
        o += scs[lk] * kvg[((size_t)b*SEQ + lk)*768 + pass*384 + DM + t];
      ov[t] = o*inv;
    }
    __syncthreads();
    coop_gemv192(wa + 3*DM*DM, ba + 3*DM, ov, pass ? feat : t1,
                 pass ? t16 : nullptr, DM, 0, wbuf, pt, t);
  }

  // own MLP hidden layer (512 outs, relu)
  coop_gemv192(path ? p1w : c1w, path ? p1b : c1b, feat, hbuf,
               nullptr, 512, 1, wbuf, pt, t);

  // own head: K=512, 16-way k-split
  {
    const int op = t & 15, ks = t >> 4;
    const int nop = path ? 3 : 10;
    float a = 0.f;
    if (op < nop) {
      const float* wr = (path ? p2w : c2w) + (size_t)op*512 + ks*32;
      const float4* w4 = (const float4*)wr;
      const float4* v4 = (const float4*)(hbuf + ks*32);
#pragma unroll
      for (int j = 0; j < 8; ++j) a += dot4(v4[j], w4[j]);
    }
    pth[op*16 + ks] = a;
  }
  __syncthreads();
  if (t < (path ? 3 : 10)) {
    float s = 0.f;
#pragma unroll
    for (int j = 0; j < 16; ++j) s += pth[t*16 + j];
    if (!path) out[b*10 + t] = s + c2b[t];
    else       out[1280 + b*3 + t] = s + p2b[t];
  }
}

extern "C" void kernel_launch(void* const* d_in, const int* in_sizes, int n_in,
                              void* d_out, int out_size, void* d_ws, size_t ws_size,
                              hipStream_t stream)
{
  (void)in_sizes; (void)n_in; (void)out_size; (void)ws_size;
  const float* x    = (const float*)d_in[0];
  const float* tpw  = (const float*)d_in[1];
  const float* tpb  = (const float*)d_in[2];
  const float* fpw  = (const float*)d_in[3];
  const float* fpb  = (const float*)d_in[4];
  const float* ttok = (const float*)d_in[5];
  const float* ftok = (const float*)d_in[6];
  const float* tpos = (const float*)d_in[7];
  const float* fpos = (const float*)d_in[8];
  MambaW wt { (const float*)d_in[9],  (const float*)d_in[10], (const float*)d_in[11],
              (const float*)d_in[12], (const float*)d_in[13], (const float*)d_in[14],
              (const float*)d_in[15], (const float*)d_in[16], (const float*)d_in[17],
              (const float*)d_in[18] };
  MambaW wf { (const float*)d_in[19], (const float*)d_in[20], (const float*)d_in[21],
              (const float*)d_in[22], (const float*)d_in[23], (const float*)d_in[24],
              (const float*)d_in[25], (const float*)d_in[26], (const float*)d_in[27],
              (const float*)d_in[28] };
  const float* attw  = (const float*)d_in[29];
  const float* attb  = (const float*)d_in[30];
  const float* attw2 = (const float*)d_in[31];
  const float* attb2 = (const float*)d_in[32];
  const float* c1w = (const float*)d_in[33];
  const float* c1b = (const float*)d_in[34];
  const float* c2w = (const float*)d_in[35];
  const float* c2b = (const float*)d_in[36];
  const float* p1w = (const float*)d_in[37];
  const float* p1b = (const float*)d_in[38];
  const float* p2w = (const float*)d_in[39];
  const float* p2b = (const float*)d_in[40];

  // ws layout byte-identical to R4. Embed-path aliases (verified R11):
  //   Cemb [835584, 3981312): 4 K-partials over xfin + xzg head.
  //   Af   [3981312, 7651328): f-stream A rows over xzg tail + part + h + yHi head.
  float* ws = (float*)d_ws;
  size_t off = 0;
  float* res  = ws + off; off += (size_t)N192;
  float* xfin = ws + off; off += (size_t)N192;
  float* xzg  = ws + off; off += (size_t)4*N192;       // NROWS x 768
  float* part = ws + off; off += (size_t)2*N192;       // 2 K-split partials (also kvg)
  unsigned short* hHi = (unsigned short*)(ws + off); off += (size_t)N192/2;
  unsigned short* hLo = (unsigned short*)(ws + off); off += (size_t)N192/2;
  unsigned short* yHi = (unsigned short*)(ws + off); off += (size_t)N192;   // NROWS x 384
  unsigned short* yLo = (unsigned short*)(ws + off); off += (size_t)N192;
  unsigned short* ipHi = (unsigned short*)(ws + off); off += (size_t)C1IP; // 2 streams
  unsigned short* ipLo = (unsigned short*)(ws + off); off += (size_t)C1IP;
  unsigned short* opHi = (unsigned short*)(ws + off); off += (size_t)C2OP;
  unsigned short* opLo = (unsigned short*)(ws + off); off += (size_t)C2OP;
  float* kvg = part;

  float* Cemb = ws + (size_t)N192;                       // 4*786432 floats
  float* Af   = ws + (size_t)N192 + (size_t)4*CEMB_STRIDE;

  decomp_kernel<<<dim3(512, 2), 256, 0, stream>>>(wt.in_proj, wf.in_proj,
                                                  ipHi, ipLo, C1IP/4);
  decomp_kernel<<<dim3(512, 2), 256, 0, stream>>>(wt.out_proj, wf.out_proj,
                                                  opHi, opLo, C2OP/4);
  prep_kernel<<<1024, 256, 0, stream>>>(x, Af);
  gemm_embed<<<dim3(3, 64, 4), 256, 0, stream>>>(x, Af, tpw, fpw, Cemb);
  embed_fin_kernel<<<256, 192, 0, stream>>>(Cemb,
      tpb, tpos, ttok, wt.norm_w,
      fpb, fpos, ftok, wf.norm_w,
      res, hHi, hLo);

  for (int i = 0; i < DEPTH; ++i) {
    const size_t ipo = (size_t)i*2*DI*DM;
    const size_t opo = (size_t)i*DM*DI;
    gemm_mfma<128><<<dim3(6, 68, 1), 256, 0, stream>>>(
        hHi, hLo, DM,
        ipHi + ipo, ipLo + ipo, ipHi + C1IP + ipo, ipLo + C1IP + ipo,
        DM, DM /*kchunk=192*/, xzg, 768, 0);
    mid_kernel<<<256, 384, 0, stream>>>(xzg, yHi, yLo, wt, wf, i);
    gemm_mfma<64><<<dim3(3, 68, 2), 256, 0, stream>>>(
        yHi, yLo, DI,
        opHi + opo, opLo + opo, opHi + C2OP + opo, opLo + C2OP + opo,
        DI, 192, part, DM, (long)N192);
    fuse_kernel<<<256, 192, 0, stream>>>(part, res, hHi, hLo, xfin,
        wt.norm_w, wf.norm_w, i, (i == DEPTH-1) ? 1 : 0);
  }

  gemm_kv<<<dim3(8, 17), 256, 0, stream>>>(
      xfin + (size_t)NB*ROW, DM, DM,
      attw, attw2, DM, attb, attb2, kvg, 768);
  attn_core_kernel<<<256, 256, 0, stream>>>(xfin, kvg,
      attw, attb, attw2, attb2,
      c1w, c1b, c2w, c2b, p1w, p1b, p2w, p2b, (float*)d_out);
}

// Round 8
// 1136.942 us; speedup vs baseline: 1.0683x; 1.0683x over previous
//
#include <hip/hip_runtime.h>
#include <math.h>

#define NB 128
#define SEQ 17
#define DM 192
#define DI 384
#define DEPTH 12
#define ROW (SEQ*DM)       // 3264
#define NROWS 4352         // 2*NB*SEQ
#define N192 (NROWS*DM)    // 835584
#define C1IP (DEPTH*2*DI*DM)   // 1769472 (one stream's in_proj elements)
#define C2OP (DEPTH*DM*DI)     // 884736  (one stream's out_proj elements)
#define KEMB 1792
#define CEMB_STRIDE 786432     // 4096*192, one K-partial of the embed gemm

typedef __attribute__((ext_vector_type(8))) short bf16x8;
typedef __attribute__((ext_vector_type(4))) float f32x4;

struct MambaW {
  const float* norm_w;
  const float* in_proj;
  const float* conv_w;
  const float* conv_b;
  const float* x_proj;
  const float* dt_w;
  const float* dt_b;
  const float* A_log;
  const float* D;
  const float* out_proj;
};

__device__ __forceinline__ float dot4(float4 a, float4 b) {
  return a.x*b.x + a.y*b.y + a.z*b.z + a.w*b.w;
}
__device__ __forceinline__ unsigned short f2bf(float f) {
  unsigned int u = __float_as_uint(f);
  u += 0x7FFFu + ((u >> 16) & 1u);
  return (unsigned short)(u >> 16);
}
__device__ __forceinline__ float bf2f(unsigned short h) {
  return __uint_as_float(((unsigned int)h) << 16);
}
__device__ __forceinline__ void split2(float v, unsigned short& h, unsigned short& l) {
  h = f2bf(v);
  l = f2bf(v - bf2f(h));
}

// ---------------------------------------------------------------------------
// Weight decompose fp32 -> bf16 hi/lo. (verified R4)
// ---------------------------------------------------------------------------
__global__ __launch_bounds__(256) void decomp_kernel(
    const float* __restrict__ s0, const float* __restrict__ s1,
    unsigned short* __restrict__ hi, unsigned short* __restrict__ lo, int nquads)
{
  const float* s = blockIdx.y ? s1 : s0;
  size_t base = (size_t)blockIdx.y * nquads;
  for (size_t i = (size_t)blockIdx.x*256 + threadIdx.x; i < (size_t)nquads;
       i += (size_t)gridDim.x*256) {
    float4 v = ((const float4*)s)[i];
    ushort4 h, l;
    split2(v.x, h.x, l.x); split2(v.y, h.y, l.y);
    split2(v.z, h.z, l.z); split2(v.w, h.w, l.w);
    ((ushort4*)hi)[base + i] = h;
    ((ushort4*)lo)[base + i] = l;
  }
}

// ---------------------------------------------------------------------------
// f-stream transpose (verified R10).
// ---------------------------------------------------------------------------
__global__ __launch_bounds__(256) void prep_kernel(
    const float* __restrict__ x, float* __restrict__ Af)
{
  const int t = threadIdx.x;
  const int b = blockIdx.x >> 3, c = blockIdx.x & 7;
  const float* xp = x + (size_t)(b*8 + c)*3584;
  __shared__ float ts[16][225];
  for (int idx = t; idx < 3584; idx += 256)
    ts[idx & 15][idx >> 4] = xp[idx];
  __syncthreads();
  for (int i4 = t; i4 < 896; i4 += 256) {
    const int p = i4 / 56, r4 = (i4 - p*56)*4;
    float4 v;
    v.x = ts[p][r4]; v.y = ts[p][r4+1]; v.z = ts[p][r4+2]; v.w = ts[p][r4+3];
    *(float4*)&Af[(size_t)(b*16 + p)*KEMB + c*224 + r4] = v;
  }
}

// ---------------------------------------------------------------------------
// fp32 embed GEMM v4. R15: XCD trio-swizzle. R7 counters: FETCH 54MB vs
// 29.4MB unique A -> the 3 mt-blocks sharing one (nt,kz) A-slice land on
// different XCDs (consecutive blockIdx round-robins). Flatten grid to 768,
// decode so a trio's blocks have blockIdx congruent mod 8 -> same XCD ->
// A-slice fetched once into that XCD's L2, re-reads are L2 hits (~200cy vs
// ~900). Bijective: 768 = 8 xcd x 32 u x 3 mt. Math/thread-mapping identical
// to verified R11.
// ---------------------------------------------------------------------------
__global__ __launch_bounds__(256) void gemm_embed(
    const float* __restrict__ x, const float* __restrict__ Af,
    const float* __restrict__ Wt, const float* __restrict__ Wf,
    float* __restrict__ C)
{
  const int t = threadIdx.x;
  // trio-swizzle decode: bidx = xcd + 8*(u*3 + mt); trio = xcd*32 + u
  const int bidx = blockIdx.x;
  const int xcd = bidx & 7;
  const int s_  = bidx >> 3;          // 0..95
  const int mt  = s_ % 3;
  const int u   = s_ / 3;             // 0..31
  const int trio = xcd*32 + u;        // 0..255
  const int nt  = trio & 63;
  const int kz  = trio >> 6;

  __shared__ float As[32][68];
  __shared__ float Bs[32][68];

  const float* Wsel = (nt < 32 ? Wt : Wf) + (size_t)(mt*64)*KEMB;

  const int srow = t >> 2;
  const int a8   = t & 3;
  const int sw   = (a8 & 1) << 4;
  const int colA = srow ^ sw;

  const int tn = t & 15;
  const int tm = t >> 4;
  float acc[4][4];
#pragma unroll
  for (int i = 0; i < 4; ++i)
#pragma unroll
    for (int j = 0; j < 4; ++j) acc[i][j] = 0.f;

  const int kbase = kz*448;
  const float* xrowbase = nullptr;
  const float* afrow    = nullptr;
  if (nt < 32) {
    const int r = nt*64 + srow;
    const int b = r >> 4, p = r & 15;
    xrowbase = x + (size_t)(b*8)*3584 + p*224 + a8*8;
  } else {
    const int r = (nt - 32)*64 + srow;
    afrow = Af + (size_t)r*KEMB + kbase + a8*8;
  }
  const float* brow = Wsel + (size_t)srow*KEMB + kbase + a8*8;

  int cblk = kz*2, rr = 0;
  float4 pa0, pa1, pb0, pb1;
  {
    const float* ar = (nt < 32) ? (xrowbase + (size_t)cblk*3584 + rr) : afrow;
    pa0 = *(const float4*)(ar + 0);
    pa1 = *(const float4*)(ar + 4);
    pb0 = *(const float4*)(brow + 0);
    pb1 = *(const float4*)(brow + 4);
  }

  for (int kt = 0; kt < 448; kt += 32) {
    As[a8*8+0][colA]=pa0.x; As[a8*8+1][colA]=pa0.y;
    As[a8*8+2][colA]=pa0.z; As[a8*8+3][colA]=pa0.w;
    As[a8*8+4][colA]=pa1.x; As[a8*8+5][colA]=pa1.y;
    As[a8*8+6][colA]=pa1.z; As[a8*8+7][colA]=pa1.w;
    Bs[a8*8+0][colA]=pb0.x; Bs[a8*8+1][colA]=pb0.y;
    Bs[a8*8+2][colA]=pb0.z; Bs[a8*8+3][colA]=pb0.w;
    Bs[a8*8+4][colA]=pb1.x; Bs[a8*8+5][colA]=pb1.y;
    Bs[a8*8+6][colA]=pb1.z; Bs[a8*8+7][colA]=pb1.w;
    __syncthreads();
    if (kt + 32 < 448) {
      rr += 32; if (rr == 224) { rr = 0; ++cblk; }
      const float* ar = (nt < 32) ? (xrowbase + (size_t)cblk*3584 + rr)
                                  : (afrow + kt + 32);
      pa0 = *(const float4*)(ar + 0);
      pa1 = *(const float4*)(ar + 4);
      const float* br = brow + kt + 32;
      pb0 = *(const float4*)(br + 0);
      pb1 = *(const float4*)(br + 4);
    }
#pragma unroll
    for (int kk = 0; kk < 32; ++kk) {
      const int xr = ((kk >> 3) & 1) << 4;
      float a[4], b[4];
      *(float4*)&a[0] = *(const float4*)&As[kk][(tn*4) ^ xr];
      *(float4*)&b[0] = *(const float4*)&Bs[kk][(tm*4) ^ xr];
#pragma unroll
      for (int i = 0; i < 4; ++i)
#pragma unroll
        for (int j = 0; j < 4; ++j) acc[i][j] = fmaf(a[i], b[j], acc[i][j]);
    }
    __syncthreads();
  }

  float* Cb = C + (size_t)kz*CEMB_STRIDE
            + (size_t)(nt*64 + tn*4)*DM + mt*64 + tm*4;
#pragma unroll
  for (int i = 0; i < 4; ++i)
    *(float4*)(Cb + (size_t)i*DM) = *(float4*)&acc[i][0];
}

// ---------------------------------------------------------------------------
// Split-bf16 MFMA GEMM — reverted to the exact verified R4 body. R14's
// register prefetch REGRESSED (~+20us over 24 dispatches): the staging loads
// are mostly L2 hits (hbuf/weights L2-resident), so there was little latency
// to hide, and the extra live registers + instructions were pure cost.
// ---------------------------------------------------------------------------
template<int MT>
__global__ __launch_bounds__(256) void gemm_mfma(
    const unsigned short* __restrict__ Ahi, const unsigned short* __restrict__ Alo, int lda,
    const unsigned short* __restrict__ BtHi, const unsigned short* __restrict__ BtLo,
    const unsigned short* __restrict__ BfHi, const unsigned short* __restrict__ BfLo,
    int ldb, int kchunk, float* __restrict__ C, int ldc, long ckstride)
{
  const int t = threadIdx.x;
  const int mt = blockIdx.x, nt = blockIdx.y, kz = blockIdx.z;
  __shared__ alignas(16) unsigned short sAh[64*40], sAl[64*40];
  __shared__ alignas(16) unsigned short sBh[MT*40], sBl[MT*40];

  const bool isT = (nt < 34);
  const unsigned short* aH = Ahi + (size_t)(nt*64)*lda + kz*kchunk;
  const unsigned short* aL = Alo + (size_t)(nt*64)*lda + kz*kchunk;
  const unsigned short* bH = (isT ? BtHi : BfHi) + (size_t)(mt*MT)*ldb + kz*kchunk;
  const unsigned short* bL = (isT ? BtLo : BfLo) + (size_t)(mt*MT)*ldb + kz*kchunk;

  const int wave = t >> 6, lane = t & 63;
  const int arow = wave*16 + (lane & 15);
  const int kb   = (lane >> 4) * 8;

  f32x4 acc[MT/16];
#pragma unroll
  for (int mb = 0; mb < MT/16; ++mb) acc[mb] = (f32x4){0.f, 0.f, 0.f, 0.f};

  const int srow = t >> 2, sseg = (t & 3) * 8;

  for (int kt = 0; kt < kchunk; kt += 32) {
    __syncthreads();
    *(uint4*)(sAh + srow*40 + sseg) = *(const uint4*)(aH + (size_t)srow*lda + kt + sseg);
    *(uint4*)(sAl + srow*40 + sseg) = *(const uint4*)(aL + (size_t)srow*lda + kt + sseg);
#pragma unroll
    for (int rep = 0; rep < MT/64; ++rep) {
      int r2 = rep*64 + srow;
      *(uint4*)(sBh + r2*40 + sseg) = *(const uint4*)(bH + (size_t)r2*ldb + kt + sseg);
      *(uint4*)(sBl + r2*40 + sseg) = *(const uint4*)(bL + (size_t)r2*ldb + kt + sseg);
    }
    __syncthreads();
    bf16x8 ah = *(const bf16x8*)(sAh + arow*40 + kb);
    bf16x8 al = *(const bf16x8*)(sAl + arow*40 + kb);
#pragma unroll
    for (int mb = 0; mb < MT/16; ++mb) {
      bf16x8 bh = *(const bf16x8*)(sBh + (mb*16 + (lane & 15))*40 + kb);
      bf16x8 bl = *(const bf16x8*)(sBl + (mb*16 + (lane & 15))*40 + kb);
      acc[mb] = __builtin_amdgcn_mfma_f32_16x16x32_bf16(al, bh, acc[mb], 0, 0, 0);
      acc[mb] = __builtin_amdgcn_mfma_f32_16x16x32_bf16(ah, bl, acc[mb], 0, 0, 0);
      acc[mb] = __builtin_amdgcn_mfma_f32_16x16x32_bf16(ah, bh, acc[mb], 0, 0, 0);
    }
  }

  float* Cb = C + (long)kz*ckstride
            + (size_t)(nt*64 + wave*16 + (lane >> 4)*4)*ldc + mt*MT + (lane & 15);
#pragma unroll
  for (int mb = 0; mb < MT/16; ++mb)
#pragma unroll
    for (int r = 0; r < 4; ++r)
      Cb[(size_t)r*ldc + mb*16] = acc[mb][r];
}

// ---------------------------------------------------------------------------
// Embed epilogue (verified R11).
// ---------------------------------------------------------------------------
__global__ __launch_bounds__(192) void embed_fin_kernel(
    const float* __restrict__ Cg,
    const float* __restrict__ bT, const float* __restrict__ posT,
    const float* __restrict__ tokT, const float* __restrict__ nwT,
    const float* __restrict__ bF, const float* __restrict__ posF,
    const float* __restrict__ tokF, const float* __restrict__ nwF,
    float* __restrict__ res,
    unsigned short* __restrict__ hHi, unsigned short* __restrict__ hLo)
{
  const int d = threadIdx.x;
  const int sb = blockIdx.x;
  const int is_f = sb >> 7, b = sb & 127;
  const float* bias = is_f ? bF : bT;
  const float* pos  = is_f ? posF : posT;
  const float* tok  = is_f ? tokF : tokT;
  const float* nw   = is_f ? nwF : nwT;
  __shared__ float sq[SEQ*192];
  __shared__ float pt[SEQ*8];
  __shared__ float sc[SEQ];

  float v[SEQ];
  const float* Crow = Cg + ((size_t)is_f*2048 + (size_t)b*16)*DM + d;
  const float add = bias[d];
#pragma unroll
  for (int l = 0; l < 16; ++l) {
    v[l] = (Crow[l*DM] + Crow[(size_t)CEMB_STRIDE + l*DM])
         + (Crow[(size_t)2*CEMB_STRIDE + l*DM] + Crow[(size_t)3*CEMB_STRIDE + l*DM])
         + add + pos[l*DM + d];
    sq[l*192 + d] = v[l]*v[l];
  }
  v[16] = tok[d] + pos[16*DM + d];
  sq[16*192 + d] = v[16]*v[16];
  __syncthreads();
  if (d < 136) {
    int l = d >> 3, j = d & 7;
    float s = 0.f;
#pragma unroll
    for (int q = 0; q < 24; ++q) s += sq[l*192 + j + 8*q];
    pt[d] = s;
  }
  __syncthreads();
  if (d < SEQ) {
    float s = 0.f;
#pragma unroll
    for (int j = 0; j < 8; ++j) s += pt[d*8 + j];
    sc[d] = rsqrtf(s*(1.0f/192.0f) + 1e-5f);
  }
  __syncthreads();
  float nwd = nw[d];
#pragma unroll
  for (int l = 0; l < SEQ; ++l) {
    size_t idx = ((size_t)sb*SEQ + l)*DM + d;
    res[idx] = v[l];
    unsigned short h, lo_;
    split2(v[l]*sc[l]*nwd, h, lo_);
    hHi[idx] = h; hLo[idx] = lo_;
  }
}

// ---------------------------------------------------------------------------
// mid_kernel (R13 remap verified: broadcast-friendly x_proj mapping).
// ---------------------------------------------------------------------------
__global__ __launch_bounds__(384) void mid_kernel(
    const float* __restrict__ xzg,
    unsigned short* __restrict__ yHi, unsigned short* __restrict__ yLo,
    MambaW wt, MambaW wf, int layer)
{
  const int t = threadIdx.x;
  const int sb = blockIdx.x;
  const MambaW W = (sb >= NB) ? wf : wt;
  __shared__ alignas(16) float lds_xx[SEQ*388];
  __shared__ alignas(16) float lds_dbl[748];
  const size_t nb = (size_t)sb*SEQ;

  float xr[SEQ];
  {
    const float4 cw = ((const float4*)(W.conv_w + (size_t)layer*DI*4))[t];
    const float cb = W.conv_b[layer*DI + t];
    float p0 = 0.f, p1 = 0.f, p2 = 0.f;
#pragma unroll
    for (int l = 0; l < SEQ; ++l) {
      float xz = xzg[(nb + l)*768 + t];
      float v = cb + xz*cw.w + p0*cw.z + p1*cw.y + p2*cw.x;
      p2 = p1; p1 = p0; p0 = xz;
      v = v / (1.f + __expf(-v));
      xr[l] = v;
      lds_xx[l*388 + t] = v;
    }
  }
  __syncthreads();

  {
    const float* XP = W.x_proj + (size_t)layer*44*DI;
#pragma unroll
    for (int rep = 0; rep < 2; ++rep) {
      int o = t + rep*384;
      if (o < 748) {
        int j = o / 17, l = o - j*17;          // R13 remap
        const float4* wr = (const float4*)(XP + j*DI);
        const float4* xv4 = (const float4*)lds_xx + l*97;
        float a = 0.f;
        for (int k4 = 0; k4 < 96; ++k4) a += dot4(xv4[k4], wr[k4]);
        lds_dbl[l*44 + j] = a;
      }
    }
  }
  __syncthreads();

  {
    const int c = t;
    const float* dwr = W.dt_w + (size_t)layer*DI*12 + c*12;
    float w0[12];
#pragma unroll
    for (int r = 0; r < 12; ++r) w0[r] = dwr[r];
    const float dtb = W.dt_b[layer*DI + c];
    const float4* alr = (const float4*)(W.A_log + (size_t)layer*DI*16) + c*4;
    float Av[16];
#pragma unroll
    for (int q = 0; q < 4; ++q) {
      float4 a4 = alr[q];
      Av[q*4+0] = -__expf(a4.x); Av[q*4+1] = -__expf(a4.y);
      Av[q*4+2] = -__expf(a4.z); Av[q*4+3] = -__expf(a4.w);
    }
    const float Dp = W.D[layer*DI + c];
    float hst[16];
#pragma unroll
    for (int n = 0; n < 16; ++n) hst[n] = 0.f;
    for (int l = 0; l < SEQ; ++l) {
      float a = dtb;
#pragma unroll
      for (int r = 0; r < 12; ++r) a += lds_dbl[l*44 + r]*w0[r];
      float dt = (a > 20.f) ? a : log1pf(__expf(a));
      float xv = xr[l];
      const float4* dbv = (const float4*)(lds_dbl + l*44 + 12);
      float4 Bq[4], Cq[4];
      Bq[0]=dbv[0]; Bq[1]=dbv[1]; Bq[2]=dbv[2]; Bq[3]=dbv[3];
      Cq[0]=dbv[4]; Cq[1]=dbv[5]; Cq[2]=dbv[6]; Cq[3]=dbv[7];
      const float* Bs = (const float*)Bq;
      const float* Cs = (const float*)Cq;
      float y = 0.f;
      float dbx = dt * xv;
#pragma unroll
      for (int n = 0; n < 16; ++n) {
        float dA = __expf(dt * Av[n]);
        float hn = dA*hst[n] + dbx*Bs[n];
        hst[n] = hn;
        y += hn*Cs[n];
      }
      y += Dp * xv;
      float zv = xzg[(nb + l)*768 + DI + c];
      y *= zv / (1.f + __expf(-zv));
      unsigned short h, lo_;
      split2(y, h, lo_);
      size_t idx = (nb + l)*DI + c;
      yHi[idx] = h; yLo[idx] = lo_;
    }
  }
}

// ---------------------------------------------------------------------------
// Sum 2 K-split partials + residual + RMSNorm (verified R4).
// ---------------------------------------------------------------------------
__global__ __launch_bounds__(192) void fuse_kernel(
    const float* __restrict__ part, float* __restrict__ res,
    unsigned short* __restrict__ hHi, unsigned short* __restrict__ hLo,
    float* __restrict__ xfin,
    const float* __restrict__ nwT, const float* __restrict__ nwF,
    int layer, int last)
{
  const int d = threadIdx.x;
  const int sb = blockIdx.x;
  const size_t nb = (size_t)sb*SEQ;
  __shared__ float sq[SEQ*192];
  __shared__ float pt[SEQ*8];
  __shared__ float sc[SEQ];

  float v[SEQ];
#pragma unroll
  for (int l = 0; l < SEQ; ++l) {
    size_t idx = (nb + l)*DM + d;
    float s = part[idx] + part[(size_t)N192 + idx];
    if (!last) {
      s += res[idx];
      res[idx] = s;
      v[l] = s;
      sq[l*192 + d] = s*s;
    } else {
      xfin[idx] = s;
    }
  }
  if (last) return;
  __syncthreads();
  if (d < 136) {
    int l = d >> 3, j = d & 7;
    float s = 0.f;
#pragma unroll
    for (int q = 0; q < 24; ++q) s += sq[l*192 + j + 8*q];
    pt[d] = s;
  }
  __syncthreads();
  if (d < SEQ) {
    float s = 0.f;
#pragma unroll
    for (int j = 0; j < 8; ++j) s += pt[d*8 + j];
    sc[d] = rsqrtf(s*(1.0f/192.0f) + 1e-5f);
  }
  __syncthreads();
  const float* nw = ((sb < NB) ? nwT : nwF) + (size_t)(layer + 1)*DM;
  float nwd = nw[d];
#pragma unroll
  for (int l = 0; l < SEQ; ++l) {
    unsigned short h, lo_;
    split2(v[l]*sc[l]*nwd, h, lo_);
    size_t idx = (nb + l)*DM + d;
    hHi[idx] = h; hLo[idx] = lo_;
  }
}

// ---------------------------------------------------------------------------
// Attention K/V GEMM (fp32 VALU, verified R3/R4). grid (8,17).
// ---------------------------------------------------------------------------
__global__ __launch_bounds__(256, 3) void gemm_kv(
    const float* __restrict__ A, int lda, int ktot,
    const float* __restrict__ Bt, const float* __restrict__ Bf, int ldb,
    const float* __restrict__ bias1, const float* __restrict__ bias2,
    float* __restrict__ C, int ldc)
{
  const int t  = threadIdx.x;
  const int mt = blockIdx.x, nt = blockIdx.y;
  __shared__ float As[32][132];
  __shared__ float Bs[32][100];

  int pass = mt >> 2, kv = (mt >> 1) & 1, half = mt & 1;
  const float* Bp = (pass ? Bf : Bt) + (size_t)(1+kv)*DM*DM + (size_t)(half*96)*ldb;
  const float* bp = (pass ? bias2 : bias1) + (1+kv)*DM + half*96;
  const float* Ap = A + (size_t)(nt*128)*lda;

  const int tn = t & 15, tm = t >> 4;
  float acc[8][6];
#pragma unroll
  for (int i = 0; i < 8; ++i)
#pragma unroll
    for (int j = 0; j < 6; ++j) acc[i][j] = 0.f;

  const int srow = t >> 1;
  const int skl  = (t & 1) * 16;

  for (int kt = 0; kt < ktot; kt += 32) {
    __syncthreads();
    {
      const float* ar = Ap + (size_t)srow*lda + kt + skl;
      float4 v0 = *(const float4*)(ar + 0);
      float4 v1 = *(const float4*)(ar + 4);
      float4 v2 = *(const float4*)(ar + 8);
      float4 v3 = *(const float4*)(ar + 12);
      As[skl+ 0][srow]=v0.x; As[skl+ 1][srow]=v0.y; As[skl+ 2][srow]=v0.z; As[skl+ 3][srow]=v0.w;
      As[skl+ 4][srow]=v1.x; As[skl+ 5][srow]=v1.y; As[skl+ 6][srow]=v1.z; As[skl+ 7][srow]=v1.w;
      As[skl+ 8][srow]=v2.x; As[skl+ 9][srow]=v2.y; As[skl+10][srow]=v2.z; As[skl+11][srow]=v2.w;
      As[skl+12][srow]=v3.x; As[skl+13][srow]=v3.y; As[skl+14][srow]=v3.z; As[skl+15][srow]=v3.w;
    }
    if (srow < 96) {
      const float* br = Bp + (size_t)srow*ldb + kt + skl;
      float4 v0 = *(const float4*)(br + 0);
      float4 v1 = *(const float4*)(br + 4);
      float4 v2 = *(const float4*)(br + 8);
      float4 v3 = *(const float4*)(br + 12);
      Bs[skl+ 0][srow]=v0.x; Bs[skl+ 1][srow]=v0.y; Bs[skl+ 2][srow]=v0.z; Bs[skl+ 3][srow]=v0.w;
      Bs[skl+ 4][srow]=v1.x; Bs[skl+ 5][srow]=v1.y; Bs[skl+ 6][srow]=v1.z; Bs[skl+ 7][srow]=v1.w;
      Bs[skl+ 8][srow]=v2.x; Bs[skl+ 9][srow]=v2.y; Bs[skl+10][srow]=v2.z; Bs[skl+11][srow]=v2.w;
      Bs[skl+12][srow]=v3.x; Bs[skl+13][srow]=v3.y; Bs[skl+14][srow]=v3.z; Bs[skl+15][srow]=v3.w;
    }
    __syncthreads();
#pragma unroll
    for (int kk = 0; kk < 32; ++kk) {
      float a[8], b[6];
      *(float4*)&a[0] = *(const float4*)&As[kk][tn*4];
      *(float4*)&a[4] = *(const float4*)&As[kk][64 + tn*4];
      *(float2*)&b[0] = *(const float2*)&Bs[kk][tm*6];
      *(float2*)&b[2] = *(const float2*)&Bs[kk][tm*6+2];
      *(float2*)&b[4] = *(const float2*)&Bs[kk][tm*6+4];
#pragma unroll
      for (int i = 0; i < 8; ++i)
#pragma unroll
        for (int j = 0; j < 6; ++j) acc[i][j] = fmaf(a[i], b[j], acc[i][j]);
    }
  }

  float* Cb = C + (size_t)(nt*128)*ldc + mt*96;
#pragma unroll
  for (int ni = 0; ni < 8; ++ni) {
    int n = (ni < 4) ? tn*4 + ni : 64 + tn*4 + (ni - 4);
    float* cr = Cb + (size_t)n*ldc;
#pragma unroll
    for (int j = 0; j < 6; ++j) cr[tm*6 + j] = acc[ni][j] + bp[tm*6 + j];
  }
}

// ---------------------------------------------------------------------------
// coop GEMV (verified R14): register prefetch + conflict-free scalar staging.
// ---------------------------------------------------------------------------
__device__ __forceinline__ void coop_gemv192(
    const float* __restrict__ W, const float* __restrict__ bias,
    const float* __restrict__ xv, float* __restrict__ y,
    const float* __restrict__ addv, int nout, int relu,
    float* __restrict__ wbuf, float* __restrict__ pt, int t)
{
  float pv[48];
#pragma unroll
  for (int i = 0; i < 48; ++i) pv[i] = W[t + i*256];
  for (int d0 = 0; d0 < nout; d0 += 64) {
    {
      int r0 = t / 192;
      int c0 = t - r0*192;
      int addr = r0*193 + c0;
      int c = c0;
#pragma unroll
      for (int i = 0; i < 48; ++i) {
        wbuf[addr] = pv[i];
        c += 64;
        const int wrap = (c >= 192);
        c -= wrap ? 192 : 0;
        addr += wrap ? 258 : 257;
      }
    }
    __syncthreads();
    if (d0 + 64 < nout) {
      const float* nsrc = W + (size_t)(d0+64)*192;
#pragma unroll
      for (int i = 0; i < 48; ++i) pv[i] = nsrc[t + i*256];
    }
    {
      const int ol = t & 63, ks = t >> 6;
      const float* wr = wbuf + ol*193 + ks*48;
      const float* xr = xv + ks*48;
      float a = 0.f;
#pragma unroll
      for (int k = 0; k < 48; ++k) a = fmaf(wr[k], xr[k], a);
      pt[ks*64 + ol] = a;
    }
    __syncthreads();
    if (t < 64) {
      float s = (pt[t] + pt[64+t]) + (pt[128+t] + pt[192+t]) + bias[d0+t];
      if (addv) s += addv[d0+t];
      if (relu) s = fmaxf(s, 0.f);
      y[d0+t] = s;
    }
    __syncthreads();
  }
}

// ---------------------------------------------------------------------------
// attn_core (verified R14): grid 256 = (b, path).
// ---------------------------------------------------------------------------
__global__ __launch_bounds__(256) void attn_core_kernel(
    const float* __restrict__ xfin, const float* __restrict__ kvg,
    const float* __restrict__ w1, const float* __restrict__ b1,
    const float* __restrict__ w2, const float* __restrict__ b2,
    const float* __restrict__ c1w, const float* __restrict__ c1b,
    const float* __restrict__ c2w, const float* __restrict__ c2b,
    const float* __restrict__ p1w, const float* __restrict__ p1b,
    const float* __restrict__ p2w, const float* __restrict__ p2b,
    float* __restrict__ out)
{
  const int t = threadIdx.x;
  const int b = blockIdx.x >> 1;
  const int path = blockIdx.x & 1;
  __shared__ float wbuf[64*193];
  __shared__ float pt[256];
  __shared__ float pth[256];
  __shared__ alignas(16) float t16[DM];
  __shared__ alignas(16) float qv[DM];
  __shared__ alignas(16) float ov[DM];
  __shared__ alignas(16) float t1[DM];
  __shared__ alignas(16) float feat[DM];
  __shared__ alignas(16) float hbuf[512];

  if (t < DM) t16[t] = xfin[((size_t)b*SEQ + 16)*DM + t];
  __syncthreads();

  for (int pass = 0; pass < 2; ++pass) {
    const float* wa = pass ? w2 : w1;
    const float* ba = pass ? b2 : b1;
    coop_gemv192(wa, ba, pass ? t1 : t16, qv, nullptr, DM, 0, wbuf, pt, t);
    if (t < DM) {
      int h = t / 24;
      float4 q0 = *(const float4*)&qv[h*24];
      float4 q1 = *(const float4*)&qv[h*24+4];
      float4 q2 = *(const float4*)&qv[h*24+8];
      float4 q3 = *(const float4*)&qv[h*24+12];
      float4 q4 = *(const float4*)&qv[h*24+16];
      float4 q5 = *(const float4*)&qv[h*24+20];
      float scs[SEQ];
      float mx = -1e30f;
#pragma unroll
      for (int lk = 0; lk < SEQ; ++lk) {
        const float4* kr = (const float4*)(kvg + ((size_t)b*SEQ + lk)*768 + pass*384 + h*24);
        float s_ = dot4(q0,kr[0]) + dot4(q1,kr[1]) + dot4(q2,kr[2])
                 + dot4(q3,kr[3]) + dot4(q4,kr[4]) + dot4(q5,kr[5]);
        s_ *= 0.20412414523193154f;
        scs[lk] = s_;
        mx = fmaxf(mx, s_);
      }
      float den = 0.f;
#pragma unroll
      for (int lk = 0; lk < SEQ; ++lk) { float e = __expf(scs[lk]-mx); scs[lk]=e; den += e; }
      float inv = 1.f/den;
      float o = 0.f;
#pragma unroll
      for (int lk = 0; lk < SEQ; ++lk)
        o += scs[lk] * kvg[((size_t)b*SEQ + lk)*768 + pass*384 + DM + t];
      ov[t] = o*inv;
    }
    __syncthreads();
    coop_gemv192(wa + 3*DM*DM, ba + 3*DM, ov, pass ? feat : t1,
                 pass ? t16 : nullptr, DM, 0, wbuf, pt, t);
  }

  coop_gemv192(path ? p1w : c1w, path ? p1b : c1b, feat, hbuf,
               nullptr, 512, 1, wbuf, pt, t);

  {
    const int op = t & 15, ks = t >> 4;
    const int nop = path ? 3 : 10;
    float a = 0.f;
    if (op < nop) {
      const float* wr = (path ? p2w : c2w) + (size_t)op*512 + ks*32;
      const float4* w4 = (const float4*)wr;
      const float4* v4 = (const float4*)(hbuf + ks*32);
#pragma unroll
      for (int j = 0; j < 8; ++j) a += dot4(v4[j], w4[j]);
    }
    pth[op*16 + ks] = a;
  }
  __syncthreads();
  if (t < (path ? 3 : 10)) {
    float s = 0.f;
#pragma unroll
    for (int j = 0; j < 16; ++j) s += pth[t*16 + j];
    if (!path) out[b*10 + t] = s + c2b[t];
    else       out[1280 + b*3 + t] = s + p2b[t];
  }
}

extern "C" void kernel_launch(void* const* d_in, const int* in_sizes, int n_in,
                              void* d_out, int out_size, void* d_ws, size_t ws_size,
                              hipStream_t stream)
{
  (void)in_sizes; (void)n_in; (void)out_size; (void)ws_size;
  const float* x    = (const float*)d_in[0];
  const float* tpw  = (const float*)d_in[1];
  const float* tpb  = (const float*)d_in[2];
  const float* fpw  = (const float*)d_in[3];
  const float* fpb  = (const float*)d_in[4];
  const float* ttok = (const float*)d_in[5];
  const float* ftok = (const float*)d_in[6];
  const float* tpos = (const float*)d_in[7];
  const float* fpos = (const float*)d_in[8];
  MambaW wt { (const float*)d_in[9],  (const float*)d_in[10], (const float*)d_in[11],
              (const float*)d_in[12], (const float*)d_in[13], (const float*)d_in[14],
              (const float*)d_in[15], (const float*)d_in[16], (const float*)d_in[17],
              (const float*)d_in[18] };
  MambaW wf { (const float*)d_in[19], (const float*)d_in[20], (const float*)d_in[21],
              (const float*)d_in[22], (const float*)d_in[23], (const float*)d_in[24],
              (const float*)d_in[25], (const float*)d_in[26], (const float*)d_in[27],
              (const float*)d_in[28] };
  const float* attw  = (const float*)d_in[29];
  const float* attb  = (const float*)d_in[30];
  const float* attw2 = (const float*)d_in[31];
  const float* attb2 = (const float*)d_in[32];
  const float* c1w = (const float*)d_in[33];
  const float* c1b = (const float*)d_in[34];
  const float* c2w = (const float*)d_in[35];
  const float* c2b = (const float*)d_in[36];
  const float* p1w = (const float*)d_in[37];
  const float* p1b = (const float*)d_in[38];
  const float* p2w = (const float*)d_in[39];
  const float* p2b = (const float*)d_in[40];

  // ws layout byte-identical to R4. Embed-path aliases (verified R11):
  //   Cemb [835584, 3981312): 4 K-partials over xfin + xzg head.
  //   Af   [3981312, 7651328): f-stream A rows over xzg tail + part + h + yHi head.
  float* ws = (float*)d_ws;
  size_t off = 0;
  float* res  = ws + off; off += (size_t)N192;
  float* xfin = ws + off; off += (size_t)N192;
  float* xzg  = ws + off; off += (size_t)4*N192;       // NROWS x 768
  float* part = ws + off; off += (size_t)2*N192;       // 2 K-split partials (also kvg)
  unsigned short* hHi = (unsigned short*)(ws + off); off += (size_t)N192/2;
  unsigned short* hLo = (unsigned short*)(ws + off); off += (size_t)N192/2;
  unsigned short* yHi = (unsigned short*)(ws + off); off += (size_t)N192;   // NROWS x 384
  unsigned short* yLo = (unsigned short*)(ws + off); off += (size_t)N192;
  unsigned short* ipHi = (unsigned short*)(ws + off); off += (size_t)C1IP; // 2 streams
  unsigned short* ipLo = (unsigned short*)(ws + off); off += (size_t)C1IP;
  unsigned short* opHi = (unsigned short*)(ws + off); off += (size_t)C2OP;
  unsigned short* opLo = (unsigned short*)(ws + off); off += (size_t)C2OP;
  float* kvg = part;

  float* Cemb = ws + (size_t)N192;                       // 4*786432 floats
  float* Af   = ws + (size_t)N192 + (size_t)4*CEMB_STRIDE;

  decomp_kernel<<<dim3(512, 2), 256, 0, stream>>>(wt.in_proj, wf.in_proj,
                                                  ipHi, ipLo, C1IP/4);
  decomp_kernel<<<dim3(512, 2), 256, 0, stream>>>(wt.out_proj, wf.out_proj,
                                                  opHi, opLo, C2OP/4);
  prep_kernel<<<1024, 256, 0, stream>>>(x, Af);
  gemm_embed<<<768, 256, 0, stream>>>(x, Af, tpw, fpw, Cemb);
  embed_fin_kernel<<<256, 192, 0, stream>>>(Cemb,
      tpb, tpos, ttok, wt.norm_w,
      fpb, fpos, ftok, wf.norm_w,
      res, hHi, hLo);

  for (int i = 0; i < DEPTH; ++i) {
    const size_t ipo = (size_t)i*2*DI*DM;
    const size_t opo = (size_t)i*DM*DI;
    // R15: in_proj gemm MT=128 -> MT=64, grid (12,68) = 816 blocks (3.2/CU):
    // probes whether the loop GEMMs are parallelism-starved at 408 blocks.
    // Output bitwise-identical (same K order, same per-element math).
    gemm_mfma<64><<<dim3(12, 68, 1), 256, 0, stream>>>(
        hHi, hLo, DM,
        ipHi + ipo, ipLo + ipo, ipHi + C1IP + ipo, ipLo + C1IP + ipo,
        DM, DM /*kchunk=192*/, xzg, 768, 0);
    mid_kernel<<<256, 384, 0, stream>>>(xzg, yHi, yLo, wt, wf, i);
    gemm_mfma<64><<<dim3(3, 68, 2), 256, 0, stream>>>(
        yHi, yLo, DI,
        opHi + opo, opLo + opo, opHi + C2OP + opo, opLo + C2OP + opo,
        DI, 192, part, DM, (long)N192);
    fuse_kernel<<<256, 192, 0, stream>>>(part, res, hHi, hLo, xfin,
        wt.norm_w, wf.norm_w, i, (i == DEPTH-1) ? 1 : 0);
  }

  gemm_kv<<<dim3(8, 17), 256, 0, stream>>>(
      xfin + (size_t)NB*ROW, DM, DM,
      attw, attw2, DM, attb, attb2, kvg, 768);
  attn_core_kernel<<<256, 256, 0, stream>>>(xfin, kvg,
      attw, attb, attw2, attb2,
      c1w, c1b, c2w, c2b, p1w, p1b, p2w, p2b, (float*)d_out);
}

// Round 9
// 1033.744 us; speedup vs baseline: 1.1749x; 1.0998x over previous
//
#include <hip/hip_runtime.h>
#include <math.h>

#define NB 128
#define SEQ 17
#define DM 192
#define DI 384
#define DEPTH 12
#define ROW (SEQ*DM)       // 3264
#define NROWS 4352         // 2*NB*SEQ
#define N192 (NROWS*DM)    // 835584
#define C1IP (DEPTH*2*DI*DM)   // 1769472 (one stream's in_proj elements)
#define C2OP (DEPTH*DM*DI)     // 884736  (one stream's out_proj elements)
#define KEMB 1792
#define CEMB_STRIDE 786432     // 4096*192, one K-partial of the embed gemm

typedef __attribute__((ext_vector_type(8))) short bf16x8;
typedef __attribute__((ext_vector_type(4))) float f32x4;

struct MambaW {
  const float* norm_w;
  const float* in_proj;
  const float* conv_w;
  const float* conv_b;
  const float* x_proj;
  const float* dt_w;
  const float* dt_b;
  const float* A_log;
  const float* D;
  const float* out_proj;
};

__device__ __forceinline__ float dot4(float4 a, float4 b) {
  return a.x*b.x + a.y*b.y + a.z*b.z + a.w*b.w;
}
__device__ __forceinline__ unsigned short f2bf(float f) {
  unsigned int u = __float_as_uint(f);
  u += 0x7FFFu + ((u >> 16) & 1u);
  return (unsigned short)(u >> 16);
}
__device__ __forceinline__ float bf2f(unsigned short h) {
  return __uint_as_float(((unsigned int)h) << 16);
}
__device__ __forceinline__ void split2(float v, unsigned short& h, unsigned short& l) {
  h = f2bf(v);
  l = f2bf(v - bf2f(h));
}

// ---------------------------------------------------------------------------
// Weight decompose fp32 -> bf16 hi/lo. (verified R4)
// ---------------------------------------------------------------------------
__global__ __launch_bounds__(256) void decomp_kernel(
    const float* __restrict__ s0, const float* __restrict__ s1,
    unsigned short* __restrict__ hi, unsigned short* __restrict__ lo, int nquads)
{
  const float* s = blockIdx.y ? s1 : s0;
  size_t base = (size_t)blockIdx.y * nquads;
  for (size_t i = (size_t)blockIdx.x*256 + threadIdx.x; i < (size_t)nquads;
       i += (size_t)gridDim.x*256) {
    float4 v = ((const float4*)s)[i];
    ushort4 h, l;
    split2(v.x, h.x, l.x); split2(v.y, h.y, l.y);
    split2(v.z, h.z, l.z); split2(v.w, h.w, l.w);
    ((ushort4*)hi)[base + i] = h;
    ((ushort4*)lo)[base + i] = l;
  }
}

// ---------------------------------------------------------------------------
// f-stream transpose (verified R10).
// ---------------------------------------------------------------------------
__global__ __launch_bounds__(256) void prep_kernel(
    const float* __restrict__ x, float* __restrict__ Af)
{
  const int t = threadIdx.x;
  const int b = blockIdx.x >> 3, c = blockIdx.x & 7;
  const float* xp = x + (size_t)(b*8 + c)*3584;
  __shared__ float ts[16][225];
  for (int idx = t; idx < 3584; idx += 256)
    ts[idx & 15][idx >> 4] = xp[idx];
  __syncthreads();
  for (int i4 = t; i4 < 896; i4 += 256) {
    const int p = i4 / 56, r4 = (i4 - p*56)*4;
    float4 v;
    v.x = ts[p][r4]; v.y = ts[p][r4+1]; v.z = ts[p][r4+2]; v.w = ts[p][r4+3];
    *(float4*)&Af[(size_t)(b*16 + p)*KEMB + c*224 + r4] = v;
  }
}

// ---------------------------------------------------------------------------
// fp32 embed GEMM v4 (verified R15: XCD trio-swizzle, FETCH 54->28.7MB).
// ---------------------------------------------------------------------------
__global__ __launch_bounds__(256) void gemm_embed(
    const float* __restrict__ x, const float* __restrict__ Af,
    const float* __restrict__ Wt, const float* __restrict__ Wf,
    float* __restrict__ C)
{
  const int t = threadIdx.x;
  const int bidx = blockIdx.x;
  const int xcd = bidx & 7;
  const int s_  = bidx >> 3;          // 0..95
  const int mt  = s_ % 3;
  const int u   = s_ / 3;             // 0..31
  const int trio = xcd*32 + u;        // 0..255
  const int nt  = trio & 63;
  const int kz  = trio >> 6;

  __shared__ float As[32][68];
  __shared__ float Bs[32][68];

  const float* Wsel = (nt < 32 ? Wt : Wf) + (size_t)(mt*64)*KEMB;

  const int srow = t >> 2;
  const int a8   = t & 3;
  const int sw   = (a8 & 1) << 4;
  const int colA = srow ^ sw;

  const int tn = t & 15;
  const int tm = t >> 4;
  float acc[4][4];
#pragma unroll
  for (int i = 0; i < 4; ++i)
#pragma unroll
    for (int j = 0; j < 4; ++j) acc[i][j] = 0.f;

  const int kbase = kz*448;
  const float* xrowbase = nullptr;
  const float* afrow    = nullptr;
  if (nt < 32) {
    const int r = nt*64 + srow;
    const int b = r >> 4, p = r & 15;
    xrowbase = x + (size_t)(b*8)*3584 + p*224 + a8*8;
  } else {
    const int r = (nt - 32)*64 + srow;
    afrow = Af + (size_t)r*KEMB + kbase + a8*8;
  }
  const float* brow = Wsel + (size_t)srow*KEMB + kbase + a8*8;

  int cblk = kz*2, rr = 0;
  float4 pa0, pa1, pb0, pb1;
  {
    const float* ar = (nt < 32) ? (xrowbase + (size_t)cblk*3584 + rr) : afrow;
    pa0 = *(const float4*)(ar + 0);
    pa1 = *(const float4*)(ar + 4);
    pb0 = *(const float4*)(brow + 0);
    pb1 = *(const float4*)(brow + 4);
  }

  for (int kt = 0; kt < 448; kt += 32) {
    As[a8*8+0][colA]=pa0.x; As[a8*8+1][colA]=pa0.y;
    As[a8*8+2][colA]=pa0.z; As[a8*8+3][colA]=pa0.w;
    As[a8*8+4][colA]=pa1.x; As[a8*8+5][colA]=pa1.y;
    As[a8*8+6][colA]=pa1.z; As[a8*8+7][colA]=pa1.w;
    Bs[a8*8+0][colA]=pb0.x; Bs[a8*8+1][colA]=pb0.y;
    Bs[a8*8+2][colA]=pb0.z; Bs[a8*8+3][colA]=pb0.w;
    Bs[a8*8+4][colA]=pb1.x; Bs[a8*8+5][colA]=pb1.y;
    Bs[a8*8+6][colA]=pb1.z; Bs[a8*8+7][colA]=pb1.w;
    __syncthreads();
    if (kt + 32 < 448) {
      rr += 32; if (rr == 224) { rr = 0; ++cblk; }
      const float* ar = (nt < 32) ? (xrowbase + (size_t)cblk*3584 + rr)
                                  : (afrow + kt + 32);
      pa0 = *(const float4*)(ar + 0);
      pa1 = *(const float4*)(ar + 4);
      const float* br = brow + kt + 32;
      pb0 = *(const float4*)(br + 0);
      pb1 = *(const float4*)(br + 4);
    }
#pragma unroll
    for (int kk = 0; kk < 32; ++kk) {
      const int xr = ((kk >> 3) & 1) << 4;
      float a[4], b[4];
      *(float4*)&a[0] = *(const float4*)&As[kk][(tn*4) ^ xr];
      *(float4*)&b[0] = *(const float4*)&Bs[kk][(tm*4) ^ xr];
#pragma unroll
      for (int i = 0; i < 4; ++i)
#pragma unroll
        for (int j = 0; j < 4; ++j) acc[i][j] = fmaf(a[i], b[j], acc[i][j]);
    }
    __syncthreads();
  }

  float* Cb = C + (size_t)kz*CEMB_STRIDE
            + (size_t)(nt*64 + tn*4)*DM + mt*64 + tm*4;
#pragma unroll
  for (int i = 0; i < 4; ++i)
    *(float4*)(Cb + (size_t)i*DM) = *(float4*)&acc[i][0];
}

// ---------------------------------------------------------------------------
// Split-bf16 MFMA GEMM (exact verified R4 body; R14 prefetch regressed).
// ---------------------------------------------------------------------------
template<int MT>
__global__ __launch_bounds__(256) void gemm_mfma(
    const unsigned short* __restrict__ Ahi, const unsigned short* __restrict__ Alo, int lda,
    const unsigned short* __restrict__ BtHi, const unsigned short* __restrict__ BtLo,
    const unsigned short* __restrict__ BfHi, const unsigned short* __restrict__ BfLo,
    int ldb, int kchunk, float* __restrict__ C, int ldc, long ckstride)
{
  const int t = threadIdx.x;
  const int mt = blockIdx.x, nt = blockIdx.y, kz = blockIdx.z;
  __shared__ alignas(16) unsigned short sAh[64*40], sAl[64*40];
  __shared__ alignas(16) unsigned short sBh[MT*40], sBl[MT*40];

  const bool isT = (nt < 34);
  const unsigned short* aH = Ahi + (size_t)(nt*64)*lda + kz*kchunk;
  const unsigned short* aL = Alo + (size_t)(nt*64)*lda + kz*kchunk;
  const unsigned short* bH = (isT ? BtHi : BfHi) + (size_t)(mt*MT)*ldb + kz*kchunk;
  const unsigned short* bL = (isT ? BtLo : BfLo) + (size_t)(mt*MT)*ldb + kz*kchunk;

  const int wave = t >> 6, lane = t & 63;
  const int arow = wave*16 + (lane & 15);
  const int kb   = (lane >> 4) * 8;

  f32x4 acc[MT/16];
#pragma unroll
  for (int mb = 0; mb < MT/16; ++mb) acc[mb] = (f32x4){0.f, 0.f, 0.f, 0.f};

  const int srow = t >> 2, sseg = (t & 3) * 8;

  for (int kt = 0; kt < kchunk; kt += 32) {
    __syncthreads();
    *(uint4*)(sAh + srow*40 + sseg) = *(const uint4*)(aH + (size_t)srow*lda + kt + sseg);
    *(uint4*)(sAl + srow*40 + sseg) = *(const uint4*)(aL + (size_t)srow*lda + kt + sseg);
#pragma unroll
    for (int rep = 0; rep < MT/64; ++rep) {
      int r2 = rep*64 + srow;
      *(uint4*)(sBh + r2*40 + sseg) = *(const uint4*)(bH + (size_t)r2*ldb + kt + sseg);
      *(uint4*)(sBl + r2*40 + sseg) = *(const uint4*)(bL + (size_t)r2*ldb + kt + sseg);
    }
    __syncthreads();
    bf16x8 ah = *(const bf16x8*)(sAh + arow*40 + kb);
    bf16x8 al = *(const bf16x8*)(sAl + arow*40 + kb);
#pragma unroll
    for (int mb = 0; mb < MT/16; ++mb) {
      bf16x8 bh = *(const bf16x8*)(sBh + (mb*16 + (lane & 15))*40 + kb);
      bf16x8 bl = *(const bf16x8*)(sBl + (mb*16 + (lane & 15))*40 + kb);
      acc[mb] = __builtin_amdgcn_mfma_f32_16x16x32_bf16(al, bh, acc[mb], 0, 0, 0);
      acc[mb] = __builtin_amdgcn_mfma_f32_16x16x32_bf16(ah, bl, acc[mb], 0, 0, 0);
      acc[mb] = __builtin_amdgcn_mfma_f32_16x16x32_bf16(ah, bh, acc[mb], 0, 0, 0);
    }
  }

  float* Cb = C + (long)kz*ckstride
            + (size_t)(nt*64 + wave*16 + (lane >> 4)*4)*ldc + mt*MT + (lane & 15);
#pragma unroll
  for (int mb = 0; mb < MT/16; ++mb)
#pragma unroll
    for (int r = 0; r < 4; ++r)
      Cb[(size_t)r*ldc + mb*16] = acc[mb][r];
}

// ---------------------------------------------------------------------------
// Embed epilogue (verified R11).
// ---------------------------------------------------------------------------
__global__ __launch_bounds__(192) void embed_fin_kernel(
    const float* __restrict__ Cg,
    const float* __restrict__ bT, const float* __restrict__ posT,
    const float* __restrict__ tokT, const float* __restrict__ nwT,
    const float* __restrict__ bF, const float* __restrict__ posF,
    const float* __restrict__ tokF, const float* __restrict__ nwF,
    float* __restrict__ res,
    unsigned short* __restrict__ hHi, unsigned short* __restrict__ hLo)
{
  const int d = threadIdx.x;
  const int sb = blockIdx.x;
  const int is_f = sb >> 7, b = sb & 127;
  const float* bias = is_f ? bF : bT;
  const float* pos  = is_f ? posF : posT;
  const float* tok  = is_f ? tokF : tokT;
  const float* nw   = is_f ? nwF : nwT;
  __shared__ float sq[SEQ*192];
  __shared__ float pt[SEQ*8];
  __shared__ float sc[SEQ];

  float v[SEQ];
  const float* Crow = Cg + ((size_t)is_f*2048 + (size_t)b*16)*DM + d;
  const float add = bias[d];
#pragma unroll
  for (int l = 0; l < 16; ++l) {
    v[l] = (Crow[l*DM] + Crow[(size_t)CEMB_STRIDE + l*DM])
         + (Crow[(size_t)2*CEMB_STRIDE + l*DM] + Crow[(size_t)3*CEMB_STRIDE + l*DM])
         + add + pos[l*DM + d];
    sq[l*192 + d] = v[l]*v[l];
  }
  v[16] = tok[d] + pos[16*DM + d];
  sq[16*192 + d] = v[16]*v[16];
  __syncthreads();
  if (d < 136) {
    int l = d >> 3, j = d & 7;
    float s = 0.f;
#pragma unroll
    for (int q = 0; q < 24; ++q) s += sq[l*192 + j + 8*q];
    pt[d] = s;
  }
  __syncthreads();
  if (d < SEQ) {
    float s = 0.f;
#pragma unroll
    for (int j = 0; j < 8; ++j) s += pt[d*8 + j];
    sc[d] = rsqrtf(s*(1.0f/192.0f) + 1e-5f);
  }
  __syncthreads();
  float nwd = nw[d];
#pragma unroll
  for (int l = 0; l < SEQ; ++l) {
    size_t idx = ((size_t)sb*SEQ + l)*DM + d;
    res[idx] = v[l];
    unsigned short h, lo_;
    split2(v[l]*sc[l]*nwd, h, lo_);
    hHi[idx] = h; hLo[idx] = lo_;
  }
}

// ---------------------------------------------------------------------------
// mid_kernel. R16: (a) #pragma unroll 8 on the x_proj k4 loop — un-unrolled,
// each iteration's global load serialized at ~L2 latency (the dominant stall
// with only 1.5 waves/SIMD); 8 loads in flight cuts it ~8x. (b) z-gate loads
// hoisted out of the serial scan loop into zr[17] (issue all 17 early).
// Both bitwise-identical (accumulation order unchanged).
// ---------------------------------------------------------------------------
__global__ __launch_bounds__(384) void mid_kernel(
    const float* __restrict__ xzg,
    unsigned short* __restrict__ yHi, unsigned short* __restrict__ yLo,
    MambaW wt, MambaW wf, int layer)
{
  const int t = threadIdx.x;
  const int sb = blockIdx.x;
  const MambaW W = (sb >= NB) ? wf : wt;
  __shared__ alignas(16) float lds_xx[SEQ*388];
  __shared__ alignas(16) float lds_dbl[748];
  const size_t nb = (size_t)sb*SEQ;

  float xr[SEQ];
  {
    const float4 cw = ((const float4*)(W.conv_w + (size_t)layer*DI*4))[t];
    const float cb = W.conv_b[layer*DI + t];
    float p0 = 0.f, p1 = 0.f, p2 = 0.f;
#pragma unroll
    for (int l = 0; l < SEQ; ++l) {
      float xz = xzg[(nb + l)*768 + t];
      float v = cb + xz*cw.w + p0*cw.z + p1*cw.y + p2*cw.x;
      p2 = p1; p1 = p0; p0 = xz;
      v = v / (1.f + __expf(-v));
      xr[l] = v;
      lds_xx[l*388 + t] = v;
    }
  }
  __syncthreads();

  {
    const float* XP = W.x_proj + (size_t)layer*44*DI;
#pragma unroll
    for (int rep = 0; rep < 2; ++rep) {
      int o = t + rep*384;
      if (o < 748) {
        int j = o / 17, l = o - j*17;          // R13 remap
        const float4* wr = (const float4*)(XP + j*DI);
        const float4* xv4 = (const float4*)lds_xx + l*97;
        float a = 0.f;
#pragma unroll 8
        for (int k4 = 0; k4 < 96; ++k4) a += dot4(xv4[k4], wr[k4]);
        lds_dbl[l*44 + j] = a;
      }
    }
  }
  __syncthreads();

  {
    const int c = t;
    const float* dwr = W.dt_w + (size_t)layer*DI*12 + c*12;
    float w0[12];
#pragma unroll
    for (int r = 0; r < 12; ++r) w0[r] = dwr[r];
    const float dtb = W.dt_b[layer*DI + c];
    const float4* alr = (const float4*)(W.A_log + (size_t)layer*DI*16) + c*4;
    float Av[16];
#pragma unroll
    for (int q = 0; q < 4; ++q) {
      float4 a4 = alr[q];
      Av[q*4+0] = -__expf(a4.x); Av[q*4+1] = -__expf(a4.y);
      Av[q*4+2] = -__expf(a4.z); Av[q*4+3] = -__expf(a4.w);
    }
    const float Dp = W.D[layer*DI + c];
    float zr[SEQ];
#pragma unroll
    for (int l = 0; l < SEQ; ++l)
      zr[l] = xzg[(nb + l)*768 + DI + c];     // R16: hoisted (early issue)
    float hst[16];
#pragma unroll
    for (int n = 0; n < 16; ++n) hst[n] = 0.f;
    for (int l = 0; l < SEQ; ++l) {
      float a = dtb;
#pragma unroll
      for (int r = 0; r < 12; ++r) a += lds_dbl[l*44 + r]*w0[r];
      float dt = (a > 20.f) ? a : log1pf(__expf(a));
      float xv = xr[l];
      const float4* dbv = (const float4*)(lds_dbl + l*44 + 12);
      float4 Bq[4], Cq[4];
      Bq[0]=dbv[0]; Bq[1]=dbv[1]; Bq[2]=dbv[2]; Bq[3]=dbv[3];
      Cq[0]=dbv[4]; Cq[1]=dbv[5]; Cq[2]=dbv[6]; Cq[3]=dbv[7];
      const float* Bs = (const float*)Bq;
      const float* Cs = (const float*)Cq;
      float y = 0.f;
      float dbx = dt * xv;
#pragma unroll
      for (int n = 0; n < 16; ++n) {
        float dA = __expf(dt * Av[n]);
        float hn = dA*hst[n] + dbx*Bs[n];
        hst[n] = hn;
        y += hn*Cs[n];
      }
      y += Dp * xv;
      float zv = zr[l];
      y *= zv / (1.f + __expf(-zv));
      unsigned short h, lo_;
      split2(y, h, lo_);
      size_t idx = (nb + l)*DI + c;
      yHi[idx] = h; yLo[idx] = lo_;
    }
  }
}

// ---------------------------------------------------------------------------
// R16 fuse_kernel v2: per-(sb,l) blocks — grid (256,17) = 4352 blocks (17/CU)
// instead of 256 (1/CU, strided loads, exposed latency). Partial-sum tree
// reproduced exactly (pt[j] = sum_q sq[j+8q], then sum_j) -> bitwise identical.
// ---------------------------------------------------------------------------
__global__ __launch_bounds__(192) void fuse_kernel(
    const float* __restrict__ part, float* __restrict__ res,
    unsigned short* __restrict__ hHi, unsigned short* __restrict__ hLo,
    float* __restrict__ xfin,
    const float* __restrict__ nwT, const float* __restrict__ nwF,
    int layer, int last)
{
  const int d = threadIdx.x;
  const int sb = blockIdx.x, l = blockIdx.y;
  const size_t idx = ((size_t)sb*SEQ + l)*DM + d;
  __shared__ float sq[192];
  __shared__ float pt[8];
  __shared__ float sc;

  float s = part[idx] + part[(size_t)N192 + idx];
  if (last) { xfin[idx] = s; return; }
  s += res[idx];
  res[idx] = s;
  sq[d] = s*s;
  __syncthreads();
  if (d < 8) {
    float p = 0.f;
#pragma unroll
    for (int q = 0; q < 24; ++q) p += sq[d + 8*q];
    pt[d] = p;
  }
  __syncthreads();
  if (d == 0) {
    float ssum = 0.f;
#pragma unroll
    for (int j = 0; j < 8; ++j) ssum += pt[j];
    sc = rsqrtf(ssum*(1.0f/192.0f) + 1e-5f);
  }
  __syncthreads();
  const float* nw = ((sb < NB) ? nwT : nwF) + (size_t)(layer + 1)*DM;
  unsigned short h, lo_;
  split2(s*sc*nw[d], h, lo_);
  hHi[idx] = h; hLo[idx] = lo_;
}

// ---------------------------------------------------------------------------
// Attention K/V GEMM (fp32 VALU, verified R3/R4). grid (8,17).
// ---------------------------------------------------------------------------
__global__ __launch_bounds__(256, 3) void gemm_kv(
    const float* __restrict__ A, int lda, int ktot,
    const float* __restrict__ Bt, const float* __restrict__ Bf, int ldb,
    const float* __restrict__ bias1, const float* __restrict__ bias2,
    float* __restrict__ C, int ldc)
{
  const int t  = threadIdx.x;
  const int mt = blockIdx.x, nt = blockIdx.y;
  __shared__ float As[32][132];
  __shared__ float Bs[32][100];

  int pass = mt >> 2, kv = (mt >> 1) & 1, half = mt & 1;
  const float* Bp = (pass ? Bf : Bt) + (size_t)(1+kv)*DM*DM + (size_t)(half*96)*ldb;
  const float* bp = (pass ? bias2 : bias1) + (1+kv)*DM + half*96;
  const float* Ap = A + (size_t)(nt*128)*lda;

  const int tn = t & 15, tm = t >> 4;
  float acc[8][6];
#pragma unroll
  for (int i = 0; i < 8; ++i)
#pragma unroll
    for (int j = 0; j < 6; ++j) acc[i][j] = 0.f;

  const int srow = t >> 1;
  const int skl  = (t & 1) * 16;

  for (int kt = 0; kt < ktot; kt += 32) {
    __syncthreads();
    {
      const float* ar = Ap + (size_t)srow*lda + kt + skl;
      float4 v0 = *(const float4*)(ar + 0);
      float4 v1 = *(const float4*)(ar + 4);
      float4 v2 = *(const float4*)(ar + 8);
      float4 v3 = *(const float4*)(ar + 12);
      As[skl+ 0][srow]=v0.x; As[skl+ 1][srow]=v0.y; As[skl+ 2][srow]=v0.z; As[skl+ 3][srow]=v0.w;
      As[skl+ 4][srow]=v1.x; As[skl+ 5][srow]=v1.y; As[skl+ 6][srow]=v1.z; As[skl+ 7][srow]=v1.w;
      As[skl+ 8][srow]=v2.x; As[skl+ 9][srow]=v2.y; As[skl+10][srow]=v2.z; As[skl+11][srow]=v2.w;
      As[skl+12][srow]=v3.x; As[skl+13][srow]=v3.y; As[skl+14][srow]=v3.z; As[skl+15][srow]=v3.w;
    }
    if (srow < 96) {
      const float* br = Bp + (size_t)srow*ldb + kt + skl;
      float4 v0 = *(const float4*)(br + 0);
      float4 v1 = *(const float4*)(br + 4);
      float4 v2 = *(const float4*)(br + 8);
      float4 v3 = *(const float4*)(br + 12);
      Bs[skl+ 0][srow]=v0.x; Bs[skl+ 1][srow]=v0.y; Bs[skl+ 2][srow]=v0.z; Bs[skl+ 3][srow]=v0.w;
      Bs[skl+ 4][srow]=v1.x; Bs[skl+ 5][srow]=v1.y; Bs[skl+ 6][srow]=v1.z; Bs[skl+ 7][srow]=v1.w;
      Bs[skl+ 8][srow]=v2.x; Bs[skl+ 9][srow]=v2.y; Bs[skl+10][srow]=v2.z; Bs[skl+11][srow]=v2.w;
      Bs[skl+12][srow]=v3.x; Bs[skl+13][srow]=v3.y; Bs[skl+14][srow]=v3.z; Bs[skl+15][srow]=v3.w;
    }
    __syncthreads();
#pragma unroll
    for (int kk = 0; kk < 32; ++kk) {
      float a[8], b[6];
      *(float4*)&a[0] = *(const float4*)&As[kk][tn*4];
      *(float4*)&a[4] = *(const float4*)&As[kk][64 + tn*4];
      *(float2*)&b[0] = *(const float2*)&Bs[kk][tm*6];
      *(float2*)&b[2] = *(const float2*)&Bs[kk][tm*6+2];
      *(float2*)&b[4] = *(const float2*)&Bs[kk][tm*6+4];
#pragma unroll
      for (int i = 0; i < 8; ++i)
#pragma unroll
        for (int j = 0; j < 6; ++j) acc[i][j] = fmaf(a[i], b[j], acc[i][j]);
    }
  }

  float* Cb = C + (size_t)(nt*128)*ldc + mt*96;
#pragma unroll
  for (int ni = 0; ni < 8; ++ni) {
    int n = (ni < 4) ? tn*4 + ni : 64 + tn*4 + (ni - 4);
    float* cr = Cb + (size_t)n*ldc;
#pragma unroll
    for (int j = 0; j < 6; ++j) cr[tm*6 + j] = acc[ni][j] + bp[tm*6 + j];
  }
}

// ---------------------------------------------------------------------------
// R16 coop GEMV v3: float2 everywhere with pad 194. R15's scalar version was
// instruction-issue-bound (48 ld + 48 st + 48 ds_read per chunk per thread;
// VALUBusy 9%, conflicts already ~0). Pad 194 -> bank = (2r+c)%32: float2
// stores 2-way (lanes t,t+16), float2 reads 2-way (lanes ol,ol+16) — both
// free (m136); 8B alignment holds on every row (194r+c even). 144 -> 72
// memory instrs/chunk. FMA order unchanged (k ascending, .x then .y).
// ---------------------------------------------------------------------------
__device__ __forceinline__ void coop_gemv192(
    const float* __restrict__ W, const float* __restrict__ bias,
    const float* __restrict__ xv, float* __restrict__ y,
    const float* __restrict__ addv, int nout, int relu,
    float* __restrict__ wbuf, float* __restrict__ pt, int t)
{
  float2 pv[24];
  const float2* W2 = (const float2*)W;
#pragma unroll
  for (int i = 0; i < 24; ++i) pv[i] = W2[t + i*256];
  for (int d0 = 0; d0 < nout; d0 += 64) {
    {
      float2* wb2 = (float2*)wbuf;
#pragma unroll
      for (int i = 0; i < 24; ++i) {
        const int g = t + i*256;      // float2 index, 96 per row
        const int r = g / 96;
        const int c2 = g - r*96;
        wb2[r*97 + c2] = pv[i];
      }
    }
    __syncthreads();
    if (d0 + 64 < nout) {
      const float2* nsrc = (const float2*)(W + (size_t)(d0+64)*192);
#pragma unroll
      for (int i = 0; i < 24; ++i) pv[i] = nsrc[t + i*256];
    }
    {
      const int ol = t & 63, ks = t >> 6;
      const float2* wr2 = (const float2*)wbuf + ol*97 + ks*24;
      const float2* xr2 = (const float2*)(xv + ks*48);
      float a = 0.f;
#pragma unroll
      for (int k = 0; k < 24; ++k) {
        float2 w2 = wr2[k], x2 = xr2[k];
        a = fmaf(w2.x, x2.x, a);
        a = fmaf(w2.y, x2.y, a);
      }
      pt[ks*64 + ol] = a;
    }
    __syncthreads();
    if (t < 64) {
      float s = (pt[t] + pt[64+t]) + (pt[128+t] + pt[192+t]) + bias[d0+t];
      if (addv) s += addv[d0+t];
      if (relu) s = fmaxf(s, 0.f);
      y[d0+t] = s;
    }
    __syncthreads();
  }
}

// ---------------------------------------------------------------------------
// attn_core (R13 structure: grid 256 = (b, path)).
// ---------------------------------------------------------------------------
__global__ __launch_bounds__(256) void attn_core_kernel(
    const float* __restrict__ xfin, const float* __restrict__ kvg,
    const float* __restrict__ w1, const float* __restrict__ b1,
    const float* __restrict__ w2, const float* __restrict__ b2,
    const float* __restrict__ c1w, const float* __restrict__ c1b,
    const float* __restrict__ c2w, const float* __restrict__ c2b,
    const float* __restrict__ p1w, const float* __restrict__ p1b,
    const float* __restrict__ p2w, const float* __restrict__ p2b,
    float* __restrict__ out)
{
  const int t = threadIdx.x;
  const int b = blockIdx.x >> 1;
  const int path = blockIdx.x & 1;
  __shared__ alignas(16) float wbuf[64*194];
  __shared__ float pt[256];
  __shared__ float pth[256];
  __shared__ alignas(16) float t16[DM];
  __shared__ alignas(16) float qv[DM];
  __shared__ alignas(16) float ov[DM];
  __shared__ alignas(16) float t1[DM];
  __shared__ alignas(16) float feat[DM];
  __shared__ alignas(16) float hbuf[512];

  if (t < DM) t16[t] = xfin[((size_t)b*SEQ + 16)*DM + t];
  __syncthreads();

  for (int pass = 0; pass < 2; ++pass) {
    const float* wa = pass ? w2 : w1;
    const float* ba = pass ? b2 : b1;
    coop_gemv192(wa, ba, pass ? t1 : t16, qv, nullptr, DM, 0, wbuf, pt, t);
    if (t < DM) {
      int h = t / 24;
      float4 q0 = *(const float4*)&qv[h*24];
      float4 q1 = *(const float4*)&qv[h*24+4];
      float4 q2 = *(const float4*)&qv[h*24+8];
      float4 q3 = *(const float4*)&qv[h*24+12];
      float4 q4 = *(const float4*)&qv[h*24+16];
      float4 q5 = *(const float4*)&qv[h*24+20];
      float scs[SEQ];
      float mx = -1e30f;
#pragma unroll
      for (int lk = 0; lk < SEQ; ++lk) {
        const float4* kr = (const float4*)(kvg + ((size_t)b*SEQ + lk)*768 + pass*384 + h*24);
        float s_ = dot4(q0,kr[0]) + dot4(q1,kr[1]) + dot4(q2,kr[2])
                 + dot4(q3,kr[3]) + dot4(q4,kr[4]) + dot4(q5,kr[5]);
        s_ *= 0.20412414523193154f;
        scs[lk] = s_;
        mx = fmaxf(mx, s_);
      }
      float den = 0.f;
#pragma unroll
      for (int lk = 0; lk < SEQ; ++lk) { float e = __expf(scs[lk]-mx); scs[lk]=e; den += e; }
      float inv = 1.f/den;
      float o = 0.f;
#pragma unroll
      for (int lk = 0; lk < SEQ; ++lk)
        o += scs[lk] * kvg[((size_t)b*SEQ + lk)*768 + pass*384 + DM + t];
      ov[t] = o*inv;
    }
    __syncthreads();
    coop_gemv192(wa + 3*DM*DM, ba + 3*DM, ov, pass ? feat : t1,
                 pass ? t16 : nullptr, DM, 0, wbuf, pt, t);
  }

  coop_gemv192(path ? p1w : c1w, path ? p1b : c1b, feat, hbuf,
               nullptr, 512, 1, wbuf, pt, t);

  {
    const int op = t & 15, ks = t >> 4;
    const int nop = path ? 3 : 10;
    float a = 0.f;
    if (op < nop) {
      const float* wr = (path ? p2w : c2w) + (size_t)op*512 + ks*32;
      const float4* w4 = (const float4*)wr;
      const float4* v4 = (const float4*)(hbuf + ks*32);
#pragma unroll
      for (int j = 0; j < 8; ++j) a += dot4(v4[j], w4[j]);
    }
    pth[op*16 + ks] = a;
  }
  __syncthreads();
  if (t < (path ? 3 : 10)) {
    float s = 0.f;
#pragma unroll
    for (int j = 0; j < 16; ++j) s += pth[t*16 + j];
    if (!path) out[b*10 + t] = s + c2b[t];
    else       out[1280 + b*3 + t] = s + p2b[t];
  }
}

extern "C" void kernel_launch(void* const* d_in, const int* in_sizes, int n_in,
                              void* d_out, int out_size, void* d_ws, size_t ws_size,
                              hipStream_t stream)
{
  (void)in_sizes; (void)n_in; (void)out_size; (void)ws_size;
  const float* x    = (const float*)d_in[0];
  const float* tpw  = (const float*)d_in[1];
  const float* tpb  = (const float*)d_in[2];
  const float* fpw  = (const float*)d_in[3];
  const float* fpb  = (const float*)d_in[4];
  const float* ttok = (const float*)d_in[5];
  const float* ftok = (const float*)d_in[6];
  const float* tpos = (const float*)d_in[7];
  const float* fpos = (const float*)d_in[8];
  MambaW wt { (const float*)d_in[9],  (const float*)d_in[10], (const float*)d_in[11],
              (const float*)d_in[12], (const float*)d_in[13], (const float*)d_in[14],
              (const float*)d_in[15], (const float*)d_in[16], (const float*)d_in[17],
              (const float*)d_in[18] };
  MambaW wf { (const float*)d_in[19], (const float*)d_in[20], (const float*)d_in[21],
              (const float*)d_in[22], (const float*)d_in[23], (const float*)d_in[24],
              (const float*)d_in[25], (const float*)d_in[26], (const float*)d_in[27],
              (const float*)d_in[28] };
  const float* attw  = (const float*)d_in[29];
  const float* attb  = (const float*)d_in[30];
  const float* attw2 = (const float*)d_in[31];
  const float* attb2 = (const float*)d_in[32];
  const float* c1w = (const float*)d_in[33];
  const float* c1b = (const float*)d_in[34];
  const float* c2w = (const float*)d_in[35];
  const float* c2b = (const float*)d_in[36];
  const float* p1w = (const float*)d_in[37];
  const float* p1b = (const float*)d_in[38];
  const float* p2w = (const float*)d_in[39];
  const float* p2b = (const float*)d_in[40];

  // ws layout byte-identical to R4. Embed-path aliases (verified R11):
  //   Cemb [835584, 3981312): 4 K-partials over xfin + xzg head.
  //   Af   [3981312, 7651328): f-stream A rows over xzg tail + part + h + yHi head.
  float* ws = (float*)d_ws;
  size_t off = 0;
  float* res  = ws + off; off += (size_t)N192;
  float* xfin = ws + off; off += (size_t)N192;
  float* xzg  = ws + off; off += (size_t)4*N192;       // NROWS x 768
  float* part = ws + off; off += (size_t)2*N192;       // 2 K-split partials (also kvg)
  unsigned short* hHi = (unsigned short*)(ws + off); off += (size_t)N192/2;
  unsigned short* hLo = (unsigned short*)(ws + off); off += (size_t)N192/2;
  unsigned short* yHi = (unsigned short*)(ws + off); off += (size_t)N192;   // NROWS x 384
  unsigned short* yLo = (unsigned short*)(ws + off); off += (size_t)N192;
  unsigned short* ipHi = (unsigned short*)(ws + off); off += (size_t)C1IP; // 2 streams
  unsigned short* ipLo = (unsigned short*)(ws + off); off += (size_t)C1IP;
  unsigned short* opHi = (unsigned short*)(ws + off); off += (size_t)C2OP;
  unsigned short* opLo = (unsigned short*)(ws + off); off += (size_t)C2OP;
  float* kvg = part;

  float* Cemb = ws + (size_t)N192;                       // 4*786432 floats
  float* Af   = ws + (size_t)N192 + (size_t)4*CEMB_STRIDE;

  decomp_kernel<<<dim3(512, 2), 256, 0, stream>>>(wt.in_proj, wf.in_proj,
                                                  ipHi, ipLo, C1IP/4);
  decomp_kernel<<<dim3(512, 2), 256, 0, stream>>>(wt.out_proj, wf.out_proj,
                                                  opHi, opLo, C2OP/4);
  prep_kernel<<<1024, 256, 0, stream>>>(x, Af);
  gemm_embed<<<768, 256, 0, stream>>>(x, Af, tpw, fpw, Cemb);
  embed_fin_kernel<<<256, 192, 0, stream>>>(Cemb,
      tpb, tpos, ttok, wt.norm_w,
      fpb, fpos, ftok, wf.norm_w,
      res, hHi, hLo);

  for (int i = 0; i < DEPTH; ++i) {
    const size_t ipo = (size_t)i*2*DI*DM;
    const size_t opo = (size_t)i*DM*DI;
    gemm_mfma<64><<<dim3(12, 68, 1), 256, 0, stream>>>(
        hHi, hLo, DM,
        ipHi + ipo, ipLo + ipo, ipHi + C1IP + ipo, ipLo + C1IP + ipo,
        DM, DM /*kchunk=192*/, xzg, 768, 0);
    mid_kernel<<<256, 384, 0, stream>>>(xzg, yHi, yLo, wt, wf, i);
    gemm_mfma<64><<<dim3(3, 68, 2), 256, 0, stream>>>(
        yHi, yLo, DI,
        opHi + opo, opLo + opo, opHi + C2OP + opo, opLo + C2OP + opo,
        DI, 192, part, DM, (long)N192);
    fuse_kernel<<<dim3(256, 17), 192, 0, stream>>>(part, res, hHi, hLo, xfin,
        wt.norm_w, wf.norm_w, i, (i == DEPTH-1) ? 1 : 0);
  }

  gemm_kv<<<dim3(8, 17), 256, 0, stream>>>(
      xfin + (size_t)NB*ROW, DM, DM,
      attw, attw2, DM, attb, attb2, kvg, 768);
  attn_core_kernel<<<256, 256, 0, stream>>>(xfin, kvg,
      attw, attb, attw2, attb2,
      c1w, c1b, c2w, c2b, p1w, p1b, p2w, p2b, (float*)d_out);
}